// Round 11
// baseline (479.576 us; speedup 1.0000x reference)
//
#include <hip/hip_runtime.h>
#include <math.h>

#define N_NODES 20000
#define DEG 32
#define F_IN 142
#define HD 128
#define NHEAD 4
#define DHEAD 32
#define N_CLS 2

#define BN_SCALE 0.9999950000374997f
#define INV_SQRT_D 0.17677669529663687f

typedef short v8s __attribute__((ext_vector_type(8)));
typedef float v4f __attribute__((ext_vector_type(4)));

// ---- bf16 helpers (manual, RNE) ----
__device__ __forceinline__ unsigned short f2bf(float f) {
    unsigned u = __float_as_uint(f);
    return (unsigned short)((u + 0x7fffu + ((u >> 16) & 1u)) >> 16);
}
__device__ __forceinline__ unsigned pack2bf(float a, float b) {
    return (unsigned)f2bf(a) | ((unsigned)f2bf(b) << 16);
}
__device__ __forceinline__ float bf2f(unsigned short s) {
    return __uint_as_float((unsigned)s << 16);
}
__device__ __forceinline__ float bflo(unsigned u) { return __uint_as_float(u << 16); }
__device__ __forceinline__ float bfhi(unsigned u) { return __uint_as_float(u & 0xffff0000u); }

__device__ __forceinline__ v8s pack8(float4 f0, float4 f1) {
    union { v8s s; unsigned u[4]; } x;
    x.u[0] = pack2bf(f0.x, f0.y);
    x.u[1] = pack2bf(f0.z, f0.w);
    x.u[2] = pack2bf(f1.x, f1.y);
    x.u[3] = pack2bf(f1.z, f1.w);
    return x.s;
}

// ---------------- kE0: E[l] = lemb[l] @ W2 + b1 + b2 (l=0..2)  [proven] ----------------
__global__ void kE0(const float* __restrict__ lemb, const float* __restrict__ W2,
                    const float* __restrict__ b1, const float* __restrict__ b2,
                    float* __restrict__ E) {
    __shared__ float sl[F_IN];
    int l = blockIdx.x, c = threadIdx.x;
    for (int f = c; f < F_IN; f += HD) sl[f] = lemb[l * F_IN + f];
    __syncthreads();
    float acc = b1[c] + b2[c];
    for (int f = 0; f < F_IN; ++f) acc += sl[f] * W2[f * HD + c];
    E[l * HD + c] = acc;
}

// ---------------- kSwiz5: fp32 W[K][128] -> bf16 B-fragment layout (5 matrices) [proven] ----------------
template<int KC, int K>
__global__ void kSwiz5(const float* Wa, const float* Wb, const float* Wc,
                       const float* Wd, const float* We, short* __restrict__ out) {
    const float* Wt[5] = {Wa, Wb, Wc, Wd, We};
    const float* W = Wt[blockIdx.y];
    const int tile = blockIdx.x;        // nt*KC + kc; grid.x = 8*KC
    const int kc = tile % KC, nt = tile / KC;
    const int L = threadIdx.x;
    const int n = nt * 16 + (L & 15);
    const int kb = kc * 32 + (L >> 4) * 8;
    short v[8] __attribute__((aligned(16)));
    #pragma unroll
    for (int j = 0; j < 8; ++j) {
        int k = kb + j;
        v[j] = (k < K) ? (short)f2bf(W[(size_t)k * HD + n]) : (short)0;
    }
    short* dst = out + (size_t)blockIdx.y * (8 * KC * 64 * 8) + ((size_t)tile * 64 + L) * 8;
    *(uint4*)dst = *(const uint4*)v;
}

// ---------------- kSwizW3: fp32 W3[128][142] -> bf16 B-frags, 9 n-tiles, KC=4 [proven] ----------------
__global__ void kSwizW3(const float* __restrict__ W3, short* __restrict__ out) {
    const int tile = blockIdx.x;        // nt*4 + kc; grid.x = 36
    const int kc = tile & 3, nt = tile >> 2;
    const int L = threadIdx.x;
    const int n = nt * 16 + (L & 15);
    const int kb = kc * 32 + (L >> 4) * 8;
    short v[8] __attribute__((aligned(16)));
    #pragma unroll
    for (int j = 0; j < 8; ++j)
        v[j] = (n < F_IN) ? (short)f2bf(W3[(size_t)(kb + j) * F_IN + n]) : (short)0;
    *(uint4*)(out + ((size_t)tile * 64 + L) * 8) = *(const uint4*)v;
}

// ---------------- kAB: fused t = PReLU(BN(feat@W1+E)), h = feat + t@W3 + b3 [proven] ----------------
__global__ __launch_bounds__(256) void kAB_m(const float* __restrict__ feat,
        const short* __restrict__ W1f, const short* __restrict__ W3f,
        const int* __restrict__ labels, const float* __restrict__ E,
        const float* __restrict__ bng, const float* __restrict__ bnb,
        const float* __restrict__ a3, const float* __restrict__ b3,
        float* __restrict__ h) {
    __shared__ float4 sAv[32 * 164 / 4];
    __shared__ uint4  sTv[32 * 136 / 8];
    __shared__ int sLab[32];
    float* sA = (float*)sAv;
    unsigned short* sT = (unsigned short*)sTv;
    const int tid = threadIdx.x;
    const int row0 = blockIdx.x * 32;
    for (int idx = tid; idx < 32 * F_IN; idx += 256) {
        int r = idx / F_IN, c = idx - r * F_IN;
        sA[r * 164 + c] = feat[(size_t)(row0 + r) * F_IN + c];
    }
    {   const int ZC = 160 - F_IN;
        for (int idx = tid; idx < 32 * ZC; idx += 256) {
            int r = idx / ZC, c = idx - r * ZC;
            sA[r * 164 + F_IN + c] = 0.f;
        }
    }
    if (tid < 32) sLab[tid] = labels[row0 + tid];
    __syncthreads();

    const int lane = tid & 63, w = tid >> 6;
    const int m = lane & 15, q = lane >> 4;
    const int nt0 = w * 2, nt1 = nt0 + 1;

    v4f acc00 = {0.f,0.f,0.f,0.f}, acc01 = acc00, acc10 = acc00, acc11 = acc00;
    #pragma unroll
    for (int kc = 0; kc < 5; ++kc) {
        const float* r0 = sA + m * 164 + kc * 32 + q * 8;
        const float* r1 = sA + (16 + m) * 164 + kc * 32 + q * 8;
        v8s a0 = pack8(*(const float4*)r0, *(const float4*)(r0 + 4));
        v8s a1 = pack8(*(const float4*)r1, *(const float4*)(r1 + 4));
        v8s b0 = *(const v8s*)(W1f + ((size_t)((nt0 * 5 + kc) * 64 + lane)) * 8);
        v8s b1 = *(const v8s*)(W1f + ((size_t)((nt1 * 5 + kc) * 64 + lane)) * 8);
        acc00 = __builtin_amdgcn_mfma_f32_16x16x32_bf16(a0, b0, acc00, 0, 0, 0);
        acc01 = __builtin_amdgcn_mfma_f32_16x16x32_bf16(a0, b1, acc01, 0, 0, 0);
        acc10 = __builtin_amdgcn_mfma_f32_16x16x32_bf16(a1, b0, acc10, 0, 0, 0);
        acc11 = __builtin_amdgcn_mfma_f32_16x16x32_bf16(a1, b1, acc11, 0, 0, 0);
    }
    const int c0 = w * 32 + m, c1 = c0 + 16;
    {
        const float g0 = bng[c0] * BN_SCALE, g1 = bng[c1] * BN_SCALE;
        const float bb0 = bnb[c0], bb1 = bnb[c1];
        const float al = a3[0];
        #pragma unroll
        for (int rt = 0; rt < 2; ++rt) {
            v4f A0 = rt ? acc10 : acc00;
            v4f A1 = rt ? acc11 : acc01;
            #pragma unroll
            for (int i = 0; i < 4; ++i) {
                const int r = rt * 16 + q * 4 + i;
                const int lab = sLab[r];
                float y0 = (A0[i] + E[lab * HD + c0]) * g0 + bb0;
                float y1 = (A1[i] + E[lab * HD + c1]) * g1 + bb1;
                y0 = (y0 >= 0.f) ? y0 : al * y0;
                y1 = (y1 >= 0.f) ? y1 : al * y1;
                sT[r * 136 + c0] = f2bf(y0);
                sT[r * 136 + c1] = f2bf(y1);
            }
        }
    }
    __syncthreads();

    v4f d00 = {0.f,0.f,0.f,0.f}, d01 = d00, d10 = d00, d11 = d00, e0 = d00, e1 = d00;
    #pragma unroll
    for (int kc = 0; kc < 4; ++kc) {
        v8s a0 = *(const v8s*)(sT + m * 136 + kc * 32 + q * 8);
        v8s a1 = *(const v8s*)(sT + (16 + m) * 136 + kc * 32 + q * 8);
        v8s b0 = *(const v8s*)(W3f + ((size_t)((nt0 * 4 + kc) * 64 + lane)) * 8);
        v8s b1 = *(const v8s*)(W3f + ((size_t)((nt1 * 4 + kc) * 64 + lane)) * 8);
        d00 = __builtin_amdgcn_mfma_f32_16x16x32_bf16(a0, b0, d00, 0, 0, 0);
        d01 = __builtin_amdgcn_mfma_f32_16x16x32_bf16(a0, b1, d01, 0, 0, 0);
        d10 = __builtin_amdgcn_mfma_f32_16x16x32_bf16(a1, b0, d10, 0, 0, 0);
        d11 = __builtin_amdgcn_mfma_f32_16x16x32_bf16(a1, b1, d11, 0, 0, 0);
        if (w == 3) {
            v8s b2 = *(const v8s*)(W3f + ((size_t)((8 * 4 + kc) * 64 + lane)) * 8);
            e0 = __builtin_amdgcn_mfma_f32_16x16x32_bf16(a0, b2, e0, 0, 0, 0);
            e1 = __builtin_amdgcn_mfma_f32_16x16x32_bf16(a1, b2, e1, 0, 0, 0);
        }
    }
    const float b30 = b3[c0], b31 = b3[c1];
    #pragma unroll
    for (int rt = 0; rt < 2; ++rt) {
        v4f D0 = rt ? d10 : d00;
        v4f D1 = rt ? d11 : d01;
        #pragma unroll
        for (int i = 0; i < 4; ++i) {
            const int r = row0 + rt * 16 + q * 4 + i;
            h[(size_t)r * F_IN + c0] = feat[(size_t)r * F_IN + c0] + D0[i] + b30;
            h[(size_t)r * F_IN + c1] = feat[(size_t)r * F_IN + c1] + D1[i] + b31;
        }
    }
    if (w == 3) {
        const int c2 = 128 + m;
        if (c2 < F_IN) {
            const float b32 = b3[c2];
            #pragma unroll
            for (int i = 0; i < 4; ++i) {
                const int ra = row0 + q * 4 + i;
                const int rb = ra + 16;
                h[(size_t)ra * F_IN + c2] = feat[(size_t)ra * F_IN + c2] + e0[i] + b32;
                h[(size_t)rb * F_IN + c2] = feat[(size_t)rb * F_IN + c2] + e1[i] + b32;
            }
        }
    }
}

// ---------------- kC4: all 4 projections in one block [proven] ----------------
template<int K, int LDSK, int KC>
__global__ __launch_bounds__(256) void kC4_mf(const float* __restrict__ A,
        const short* __restrict__ WfBase,
        const float* __restrict__ bq, const float* __restrict__ bk,
        const float* __restrict__ bv, const float* __restrict__ bs,
        unsigned short* __restrict__ qh, unsigned short* __restrict__ kh,
        unsigned short* __restrict__ vh, float* __restrict__ sOut) {
    __shared__ float4 sAv[32 * LDSK / 4];
    float* sA = (float*)sAv;
    const int tid = threadIdx.x;
    const int row0 = blockIdx.x * 32;
    for (int idx = tid; idx < 32 * K; idx += 256) {
        int r = idx / K, c = idx - r * K;
        sA[r * LDSK + c] = A[(size_t)(row0 + r) * K + c];
    }
    if (K < KC * 32) {
        const int ZC = KC * 32 - K;
        for (int idx = tid; idx < 32 * ZC; idx += 256) {
            int r = idx / ZC, c = idx - r * ZC;
            sA[r * LDSK + K + c] = 0.f;
        }
    }
    __syncthreads();

    const int lane = tid & 63, w = tid >> 6;
    const int m = lane & 15, q = lane >> 4;
    const int nt0 = w * 2, nt1 = nt0 + 1;

    v8s afr0[KC], afr1[KC];
    #pragma unroll
    for (int kc = 0; kc < KC; ++kc) {
        const float* r0 = sA + m * LDSK + kc * 32 + q * 8;
        const float* r1 = sA + (16 + m) * LDSK + kc * 32 + q * 8;
        afr0[kc] = pack8(*(const float4*)r0, *(const float4*)(r0 + 4));
        afr1[kc] = pack8(*(const float4*)r1, *(const float4*)(r1 + 4));
    }

    const int c0 = w * 32 + m, c1 = c0 + 16;
    #pragma unroll
    for (int mat = 0; mat < 4; ++mat) {
        const short* Wf = WfBase + (size_t)mat * (KC * 4096);
        const float* bias = (mat == 0) ? bq : (mat == 1) ? bk : (mat == 2) ? bv : bs;
        v4f acc00 = {0.f,0.f,0.f,0.f}, acc01 = acc00, acc10 = acc00, acc11 = acc00;
        #pragma unroll
        for (int kc = 0; kc < KC; ++kc) {
            v8s b0 = *(const v8s*)(Wf + ((size_t)((nt0 * KC + kc) * 64 + lane)) * 8);
            v8s b1 = *(const v8s*)(Wf + ((size_t)((nt1 * KC + kc) * 64 + lane)) * 8);
            acc00 = __builtin_amdgcn_mfma_f32_16x16x32_bf16(afr0[kc], b0, acc00, 0, 0, 0);
            acc01 = __builtin_amdgcn_mfma_f32_16x16x32_bf16(afr0[kc], b1, acc01, 0, 0, 0);
            acc10 = __builtin_amdgcn_mfma_f32_16x16x32_bf16(afr1[kc], b0, acc10, 0, 0, 0);
            acc11 = __builtin_amdgcn_mfma_f32_16x16x32_bf16(afr1[kc], b1, acc11, 0, 0, 0);
        }
        const float b0v = bias[c0], b1v = bias[c1];
        if (mat < 3) {
            unsigned short* outh = (mat == 0) ? qh : (mat == 1) ? kh : vh;
            unsigned short* outw = outh + ((size_t)w * N_NODES + row0) * DHEAD;
            #pragma unroll
            for (int rt = 0; rt < 2; ++rt) {
                v4f A0 = rt ? acc10 : acc00;
                v4f A1 = rt ? acc11 : acc01;
                #pragma unroll
                for (int i = 0; i < 4; ++i) {
                    const int r = rt * 16 + q * 4 + i;
                    outw[(size_t)r * DHEAD + m]      = f2bf(A0[i] + b0v);
                    outw[(size_t)r * DHEAD + 16 + m] = f2bf(A1[i] + b1v);
                }
            }
        } else {
            #pragma unroll
            for (int rt = 0; rt < 2; ++rt) {
                v4f A0 = rt ? acc10 : acc00;
                v4f A1 = rt ? acc11 : acc01;
                #pragma unroll
                for (int i = 0; i < 4; ++i) {
                    const int r = rt * 16 + q * 4 + i;
                    sOut[(size_t)(row0 + r) * HD + c0] = A0[i] + b0v;
                    sOut[(size_t)(row0 + r) * HD + c1] = A1[i] + b1v;
                }
            }
        }
    }
}

// ---------------- kDE_w: wave-per-2-nodes attention + fused gate/LN/PReLU ----------------
// 8 nodes/block; wave w owns nodes {2w, 2w+1} and loops the 4 heads internally.
// All head-phase state (sa) is wave-local LDS -> no inter-head barriers.
// Only 2 block barriers: after ssrc staging, before the fused LN epilogue.
__global__ __launch_bounds__(256) void kDE_w(const unsigned short* __restrict__ qh,
        const unsigned short* __restrict__ kh, const unsigned short* __restrict__ vh,
        const int* __restrict__ esrc, const float* __restrict__ skip,
        const float* __restrict__ Wg, const float* __restrict__ bg,
        const float* __restrict__ lng, const float* __restrict__ lnb,
        const float* __restrict__ ac, float* __restrict__ hout) {
    __shared__ int ssrc[8][DEG];
    __shared__ float sa[NHEAD][2][DEG];   // per-wave scratch (wave w -> sa[w])
    __shared__ float sAgg[8][HD];
    const int n0 = blockIdx.x * 8;
    const int t = threadIdx.x;
    const int w = t >> 6, lane = t & 63;
    const int half = lane >> 5, e = lane & 31;
    const int j = w * 2 + half;           // node index 0..7 owned by this lane

    ssrc[t >> 5][t & 31] = esrc[n0 * DEG + t];
    __syncthreads();

    const int src = ssrc[j][e];           // this lane's edge source (fixed across heads)

    for (int h = 0; h < NHEAD; ++h) {
        // k row of node j for head h: same address across the 32 lanes of this half-wave
        const uint4* kp = (const uint4*)(kh + ((size_t)h * N_NODES + (n0 + j)) * DHEAD);
        const uint4 k0 = kp[0], k1 = kp[1], k2 = kp[2], k3 = kp[3];
        const uint4* qp = (const uint4*)(qh + ((size_t)h * N_NODES + src) * DHEAD);
        float sc = 0.f;
        uint4 u;
        u = qp[0];
        sc = fmaf(bflo(u.x), bflo(k0.x), sc); sc = fmaf(bfhi(u.x), bfhi(k0.x), sc);
        sc = fmaf(bflo(u.y), bflo(k0.y), sc); sc = fmaf(bfhi(u.y), bfhi(k0.y), sc);
        sc = fmaf(bflo(u.z), bflo(k0.z), sc); sc = fmaf(bfhi(u.z), bfhi(k0.z), sc);
        sc = fmaf(bflo(u.w), bflo(k0.w), sc); sc = fmaf(bfhi(u.w), bfhi(k0.w), sc);
        u = qp[1];
        sc = fmaf(bflo(u.x), bflo(k1.x), sc); sc = fmaf(bfhi(u.x), bfhi(k1.x), sc);
        sc = fmaf(bflo(u.y), bflo(k1.y), sc); sc = fmaf(bfhi(u.y), bfhi(k1.y), sc);
        sc = fmaf(bflo(u.z), bflo(k1.z), sc); sc = fmaf(bfhi(u.z), bfhi(k1.z), sc);
        sc = fmaf(bflo(u.w), bflo(k1.w), sc); sc = fmaf(bfhi(u.w), bfhi(k1.w), sc);
        u = qp[2];
        sc = fmaf(bflo(u.x), bflo(k2.x), sc); sc = fmaf(bfhi(u.x), bfhi(k2.x), sc);
        sc = fmaf(bflo(u.y), bflo(k2.y), sc); sc = fmaf(bfhi(u.y), bfhi(k2.y), sc);
        sc = fmaf(bflo(u.z), bflo(k2.z), sc); sc = fmaf(bfhi(u.z), bfhi(k2.z), sc);
        sc = fmaf(bflo(u.w), bflo(k2.w), sc); sc = fmaf(bfhi(u.w), bfhi(k2.w), sc);
        u = qp[3];
        sc = fmaf(bflo(u.x), bflo(k3.x), sc); sc = fmaf(bfhi(u.x), bfhi(k3.x), sc);
        sc = fmaf(bflo(u.y), bflo(k3.y), sc); sc = fmaf(bfhi(u.y), bfhi(k3.y), sc);
        sc = fmaf(bflo(u.z), bflo(k3.z), sc); sc = fmaf(bfhi(u.z), bfhi(k3.z), sc);
        sc = fmaf(bflo(u.w), bflo(k3.w), sc); sc = fmaf(bfhi(u.w), bfhi(k3.w), sc);
        sc *= INV_SQRT_D;

        float mx = sc;
        #pragma unroll
        for (int off = 16; off > 0; off >>= 1)
            mx = fmaxf(mx, __shfl_xor(mx, off, 32));
        float p = expf(sc - mx);
        float ssum = p;
        #pragma unroll
        for (int off = 16; off > 0; off >>= 1)
            ssum += __shfl_xor(ssum, off, 32);
        sa[w][half][e] = p / ssum;   // wave-local; program order + lgkmcnt suffice

        // aggregation: lane (half, d=e) -> node j, dim e
        const unsigned short* vbase = vh + (size_t)h * N_NODES * DHEAD + e;
        float acc = 0.f;
        #pragma unroll
        for (int e2 = 0; e2 < DEG; ++e2)
            acc = fmaf(bf2f(vbase[(size_t)ssrc[j][e2] * DHEAD]), sa[w][half][e2], acc);
        sAgg[j][h * DHEAD + e] = acc;
    }
    __syncthreads();

    // ---- fused gate + LayerNorm + PReLU: node t>>5, lane e handles channels e+32k ----
    const int jn = t >> 5;
    const int n = n0 + jn;
    const int ee = t & 31;
    float skv[4], agv[4];
    float part = 0.f;
    #pragma unroll
    for (int k2 = 0; k2 < 4; ++k2) {
        const int c = ee + 32 * k2;
        skv[k2] = skip[(size_t)n * HD + c];
        agv[k2] = sAgg[jn][c];
        part += skv[k2] * Wg[c] + agv[k2] * Wg[HD + c] + (skv[k2] - agv[k2]) * Wg[2 * HD + c];
    }
    #pragma unroll
    for (int off = 16; off > 0; off >>= 1)
        part += __shfl_xor(part, off, 32);
    const float z = part + bg[0];
    const float g = 1.f / (1.f + expf(-z));
    float rv[4], rsum = 0.f;
    #pragma unroll
    for (int k2 = 0; k2 < 4; ++k2) {
        rv[k2] = g * skv[k2] + (1.f - g) * agv[k2];
        rsum += rv[k2];
    }
    #pragma unroll
    for (int off = 16; off > 0; off >>= 1)
        rsum += __shfl_xor(rsum, off, 32);
    const float mean = rsum * (1.f / HD);
    float dv[4], vsum = 0.f;
    #pragma unroll
    for (int k2 = 0; k2 < 4; ++k2) {
        dv[k2] = rv[k2] - mean;
        vsum += dv[k2] * dv[k2];
    }
    #pragma unroll
    for (int off = 16; off > 0; off >>= 1)
        vsum += __shfl_xor(vsum, off, 32);
    const float inv = rsqrtf(vsum * (1.f / HD) + 1e-5f);
    const float al = ac[0];
    #pragma unroll
    for (int k2 = 0; k2 < 4; ++k2) {
        const int c = ee + 32 * k2;
        float y = dv[k2] * inv * lng[c] + lnb[c];
        y = (y >= 0.f) ? y : al * y;
        hout[(size_t)n * HD + c] = y;
    }
}

// ---------------- kF (MFMA, raceless LDS epilogue) [proven] ----------------
__global__ __launch_bounds__(256) void kF_mf2(const float* __restrict__ A,
        const short* __restrict__ W4f, const float* __restrict__ b4,
        const float* __restrict__ bng, const float* __restrict__ bnb,
        const float* __restrict__ a5, const float* __restrict__ W5,
        const float* __restrict__ b5, float* __restrict__ out) {
    __shared__ float4 sAv[32 * 132 / 4];
    float* sA = (float*)sAv;
    const int tid = threadIdx.x;
    const int row0 = blockIdx.x * 32;
    for (int idx = tid; idx < 32 * HD; idx += 256) {
        int r = idx >> 7, c = idx & 127;
        sA[r * 132 + c] = A[(size_t)(row0 + r) * HD + c];
    }
    __syncthreads();
    const int lane = tid & 63, w = tid >> 6;
    const int m = lane & 15, q = lane >> 4;
    const int nt0 = w * 2, nt1 = nt0 + 1;
    v4f acc00 = {0.f,0.f,0.f,0.f}, acc01 = acc00, acc10 = acc00, acc11 = acc00;
    #pragma unroll
    for (int kc = 0; kc < 4; ++kc) {
        const float* r0 = sA + m * 132 + kc * 32 + q * 8;
        const float* r1 = sA + (16 + m) * 132 + kc * 32 + q * 8;
        v8s a0 = pack8(*(const float4*)r0, *(const float4*)(r0 + 4));
        v8s a1 = pack8(*(const float4*)r1, *(const float4*)(r1 + 4));
        v8s b0 = *(const v8s*)(W4f + ((size_t)((nt0 * 4 + kc) * 64 + lane)) * 8);
        v8s b1 = *(const v8s*)(W4f + ((size_t)((nt1 * 4 + kc) * 64 + lane)) * 8);
        acc00 = __builtin_amdgcn_mfma_f32_16x16x32_bf16(a0, b0, acc00, 0, 0, 0);
        acc01 = __builtin_amdgcn_mfma_f32_16x16x32_bf16(a0, b1, acc01, 0, 0, 0);
        acc10 = __builtin_amdgcn_mfma_f32_16x16x32_bf16(a1, b0, acc10, 0, 0, 0);
        acc11 = __builtin_amdgcn_mfma_f32_16x16x32_bf16(a1, b1, acc11, 0, 0, 0);
    }
    __syncthreads();
    const int c0 = w * 32 + m, c1 = c0 + 16;
    const float g0 = bng[c0] * BN_SCALE, g1 = bng[c1] * BN_SCALE;
    const float bb0 = bnb[c0], bb1 = bnb[c1];
    const float b40 = b4[c0], b41 = b4[c1];
    const float al = a5[0];
    #pragma unroll
    for (int rt = 0; rt < 2; ++rt) {
        v4f A0 = rt ? acc10 : acc00;
        v4f A1 = rt ? acc11 : acc01;
        #pragma unroll
        for (int i = 0; i < 4; ++i) {
            const int r = rt * 16 + q * 4 + i;
            float y0 = (A0[i] + b40) * g0 + bb0;
            float y1 = (A1[i] + b41) * g1 + bb1;
            y0 = (y0 >= 0.f) ? y0 : al * y0;
            y1 = (y1 >= 0.f) ? y1 : al * y1;
            sA[r * 132 + c0] = y0;
            sA[r * 132 + c1] = y1;
        }
    }
    __syncthreads();
    if (tid < 64) {
        const int r = tid >> 1, cls = tid & 1;
        const float* yr = sA + r * 132;
        float s = b5[cls];
        #pragma unroll 8
        for (int c = 0; c < HD; ++c)
            s = fmaf(yr[c], W5[c * 2 + cls], s);
        out[(size_t)(row0 + r) * N_CLS + cls] = s;
    }
}

extern "C" void kernel_launch(void* const* d_in, const int* in_sizes, int n_in,
                              void* d_out, int out_size, void* d_ws, size_t ws_size,
                              hipStream_t stream) {
    const float* feat  = (const float*)d_in[0];
    const float* lemb  = (const float*)d_in[1];
    const float* W1    = (const float*)d_in[2];
    const float* b1    = (const float*)d_in[3];
    const float* W2    = (const float*)d_in[4];
    const float* b2    = (const float*)d_in[5];
    const float* bn0g  = (const float*)d_in[6];
    const float* bn0b  = (const float*)d_in[7];
    const float* a3    = (const float*)d_in[8];
    const float* W3    = (const float*)d_in[9];
    const float* b3    = (const float*)d_in[10];
    const float* aconv = (const float*)d_in[35];
    const float* W4    = (const float*)d_in[36];
    const float* b4    = (const float*)d_in[37];
    const float* bn1g  = (const float*)d_in[38];
    const float* bn1b  = (const float*)d_in[39];
    const float* a5    = (const float*)d_in[40];
    const float* W5    = (const float*)d_in[41];
    const float* b5    = (const float*)d_in[42];
    const int*   labels = (const int*)d_in[43];
    const int*   esrc   = (const int*)d_in[44];

    char* ws = (char*)d_ws;
    float* bh  = (float*)ws;                       ws += sizeof(float) * N_NODES * F_IN;
    float* bs  = (float*)ws;                       ws += sizeof(float) * N_NODES * HD;
    float* bh2 = (float*)ws;                       ws += sizeof(float) * N_NODES * HD;
    unsigned short* bqh = (unsigned short*)ws;     ws += sizeof(short) * N_NODES * HD;
    unsigned short* bkh = (unsigned short*)ws;     ws += sizeof(short) * N_NODES * HD;
    unsigned short* bvh = (unsigned short*)ws;     ws += sizeof(short) * N_NODES * HD;
    short* Wf142 = (short*)ws;                     ws += sizeof(short) * 5 * 20480;  // W1,q0,k0,v0,s0
    short* Wf128 = (short*)ws;                     ws += sizeof(short) * 5 * 16384;  // q1,k1,v1,s1,W4
    short* W3f = (short*)ws;                       ws += sizeof(short) * 36 * 512;   // W3
    float* bE  = (float*)ws;                       ws += sizeof(float) * 3 * HD;     // E table
    float* out = (float*)d_out;

    dim3 gT(N_NODES / 32);
    dim3 gDE(N_NODES / 8);

    kE0<<<dim3(3), HD, 0, stream>>>(lemb, W2, b1, b2, bE);
    kSwiz5<5, F_IN><<<dim3(40, 5), 64, 0, stream>>>(W1,
        (const float*)d_in[11], (const float*)d_in[13],
        (const float*)d_in[15], (const float*)d_in[17], Wf142);
    kSwiz5<4, HD><<<dim3(32, 5), 64, 0, stream>>>(
        (const float*)d_in[23], (const float*)d_in[25],
        (const float*)d_in[27], (const float*)d_in[29], W4, Wf128);
    kSwizW3<<<dim3(36), 64, 0, stream>>>(W3, W3f);

    kAB_m<<<gT, 256, 0, stream>>>(feat, Wf142, W3f, labels, bE, bn0g, bn0b, a3, b3, bh);

    // conv layer 0 (K=142 -> LDSK=164, KC=5; projection weights at slots 1..4)
    kC4_mf<F_IN, 164, 5><<<gT, 256, 0, stream>>>(bh, Wf142 + 20480,
        (const float*)d_in[12], (const float*)d_in[14],
        (const float*)d_in[16], (const float*)d_in[18],
        bqh, bkh, bvh, bs);
    kDE_w<<<gDE, 256, 0, stream>>>(bqh, bkh, bvh, esrc, bs,
        (const float*)d_in[19], (const float*)d_in[20],
        (const float*)d_in[21], (const float*)d_in[22], aconv, bh2);

    // conv layer 1 (K=128 -> LDSK=132, KC=4; projection weights at slots 0..3)
    kC4_mf<HD, 132, 4><<<gT, 256, 0, stream>>>(bh2, Wf128,
        (const float*)d_in[24], (const float*)d_in[26],
        (const float*)d_in[28], (const float*)d_in[30],
        bqh, bkh, bvh, bs);
    kDE_w<<<gDE, 256, 0, stream>>>(bqh, bkh, bvh, esrc, bs,
        (const float*)d_in[31], (const float*)d_in[32],
        (const float*)d_in[33], (const float*)d_in[34], aconv, bh2);

    kF_mf2<<<gT, 256, 0, stream>>>(bh2, Wf128 + 4 * 16384, b4, bn1g, bn1b, a5, W5, b5, out);
}

// Round 12
// 313.712 us; speedup vs baseline: 1.5287x; 1.5287x over previous
//
#include <hip/hip_runtime.h>
#include <math.h>

#define N_NODES 20000
#define DEG 32
#define F_IN 142
#define HD 128
#define NHEAD 4
#define DHEAD 32
#define N_CLS 2

#define BN_SCALE 0.9999950000374997f
#define INV_SQRT_D 0.17677669529663687f

typedef short v8s __attribute__((ext_vector_type(8)));
typedef float v4f __attribute__((ext_vector_type(4)));

// ---- bf16 helpers (manual, RNE) ----
__device__ __forceinline__ unsigned short f2bf(float f) {
    unsigned u = __float_as_uint(f);
    return (unsigned short)((u + 0x7fffu + ((u >> 16) & 1u)) >> 16);
}
__device__ __forceinline__ unsigned pack2bf(float a, float b) {
    return (unsigned)f2bf(a) | ((unsigned)f2bf(b) << 16);
}
__device__ __forceinline__ float bf2f(unsigned short s) {
    return __uint_as_float((unsigned)s << 16);
}
__device__ __forceinline__ float bflo(unsigned u) { return __uint_as_float(u << 16); }
__device__ __forceinline__ float bfhi(unsigned u) { return __uint_as_float(u & 0xffff0000u); }

__device__ __forceinline__ v8s pack8(float4 f0, float4 f1) {
    union { v8s s; unsigned u[4]; } x;
    x.u[0] = pack2bf(f0.x, f0.y);
    x.u[1] = pack2bf(f0.z, f0.w);
    x.u[2] = pack2bf(f1.x, f1.y);
    x.u[3] = pack2bf(f1.z, f1.w);
    return x.s;
}

// ---- swizzle helper (proven kSwiz5 body): one tile of one matrix ----
__device__ __forceinline__ void swizTile(const float* __restrict__ W, int K, int KC,
                                         int tile, int L, short* __restrict__ outBase) {
    const int kc = tile % KC, nt = tile / KC;
    const int n = nt * 16 + (L & 15);
    const int kb = kc * 32 + (L >> 4) * 8;
    short v[8] __attribute__((aligned(16)));
    #pragma unroll
    for (int j = 0; j < 8; ++j) {
        int k = kb + j;
        v[j] = (k < K) ? (short)f2bf(W[(size_t)k * HD + n]) : (short)0;
    }
    *(uint4*)(outBase + ((size_t)tile * 64 + L) * 8) = *(const uint4*)v;
}

// ---------------- kPrep: ALL weight prep in one launch ----------------
// blocks [0,100): Wf142 (5 mats x 40 tiles, 2 tiles/block)
// blocks [100,180): Wf128 (5 mats x 32 tiles, 2 tiles/block)
// blocks [180,198): W3f (36 tiles, 2 tiles/block)
// blocks [198,201): E[l] = lemb[l] @ W2 + b1 + b2
__global__ __launch_bounds__(128) void kPrep(
        const float* W142a, const float* W142b, const float* W142c,
        const float* W142d, const float* W142e,
        const float* W128a, const float* W128b, const float* W128c,
        const float* W128d, const float* W128e,
        const float* __restrict__ W3,
        const float* __restrict__ lemb, const float* __restrict__ W2,
        const float* __restrict__ b1, const float* __restrict__ b2,
        short* __restrict__ Wf142, short* __restrict__ Wf128,
        short* __restrict__ W3f, float* __restrict__ E) {
    const int b = blockIdx.x;
    const int t = threadIdx.x;
    if (b < 100) {
        const float* Wt[5] = {W142a, W142b, W142c, W142d, W142e};
        const int idx = b * 2 + (t >> 6);        // flattened (mat, tile): mat*40 + tile
        const int mat = idx / 40, tile = idx - mat * 40;
        swizTile(Wt[mat], F_IN, 5, tile, t & 63, Wf142 + (size_t)mat * 20480);
    } else if (b < 180) {
        const float* Wt[5] = {W128a, W128b, W128c, W128d, W128e};
        const int idx = (b - 100) * 2 + (t >> 6); // mat*32 + tile
        const int mat = idx >> 5, tile = idx & 31;
        swizTile(Wt[mat], HD, 4, tile, t & 63, Wf128 + (size_t)mat * 16384);
    } else if (b < 198) {
        // W3 [128][142] -> 9 n-tiles x 4 kc (proven kSwizW3 body)
        const int tile = (b - 180) * 2 + (t >> 6);
        const int kc = tile & 3, nt = tile >> 2;
        const int L = t & 63;
        const int n = nt * 16 + (L & 15);
        const int kb = kc * 32 + (L >> 4) * 8;
        short v[8] __attribute__((aligned(16)));
        #pragma unroll
        for (int j = 0; j < 8; ++j)
            v[j] = (n < F_IN) ? (short)f2bf(W3[(size_t)(kb + j) * F_IN + n]) : (short)0;
        *(uint4*)(W3f + ((size_t)tile * 64 + L) * 8) = *(const uint4*)v;
    } else {
        __shared__ float sl[F_IN];
        const int l = b - 198;
        for (int f = t; f < F_IN; f += 128) sl[f] = lemb[l * F_IN + f];
        __syncthreads();
        float acc = b1[t] + b2[t];
        for (int f = 0; f < F_IN; ++f) acc += sl[f] * W2[f * HD + t];
        E[l * HD + t] = acc;
    }
}

// ---------------- kAB: fused t = PReLU(BN(feat@W1+E)), h = feat + t@W3 + b3 [proven] ----------------
__global__ __launch_bounds__(256) void kAB_m(const float* __restrict__ feat,
        const short* __restrict__ W1f, const short* __restrict__ W3f,
        const int* __restrict__ labels, const float* __restrict__ E,
        const float* __restrict__ bng, const float* __restrict__ bnb,
        const float* __restrict__ a3, const float* __restrict__ b3,
        float* __restrict__ h) {
    __shared__ float4 sAv[32 * 164 / 4];
    __shared__ uint4  sTv[32 * 136 / 8];
    __shared__ int sLab[32];
    float* sA = (float*)sAv;
    unsigned short* sT = (unsigned short*)sTv;
    const int tid = threadIdx.x;
    const int row0 = blockIdx.x * 32;
    for (int idx = tid; idx < 32 * F_IN; idx += 256) {
        int r = idx / F_IN, c = idx - r * F_IN;
        sA[r * 164 + c] = feat[(size_t)(row0 + r) * F_IN + c];
    }
    {   const int ZC = 160 - F_IN;
        for (int idx = tid; idx < 32 * ZC; idx += 256) {
            int r = idx / ZC, c = idx - r * ZC;
            sA[r * 164 + F_IN + c] = 0.f;
        }
    }
    if (tid < 32) sLab[tid] = labels[row0 + tid];
    __syncthreads();

    const int lane = tid & 63, w = tid >> 6;
    const int m = lane & 15, q = lane >> 4;
    const int nt0 = w * 2, nt1 = nt0 + 1;

    v4f acc00 = {0.f,0.f,0.f,0.f}, acc01 = acc00, acc10 = acc00, acc11 = acc00;
    #pragma unroll
    for (int kc = 0; kc < 5; ++kc) {
        const float* r0 = sA + m * 164 + kc * 32 + q * 8;
        const float* r1 = sA + (16 + m) * 164 + kc * 32 + q * 8;
        v8s a0 = pack8(*(const float4*)r0, *(const float4*)(r0 + 4));
        v8s a1 = pack8(*(const float4*)r1, *(const float4*)(r1 + 4));
        v8s b0 = *(const v8s*)(W1f + ((size_t)((nt0 * 5 + kc) * 64 + lane)) * 8);
        v8s b1 = *(const v8s*)(W1f + ((size_t)((nt1 * 5 + kc) * 64 + lane)) * 8);
        acc00 = __builtin_amdgcn_mfma_f32_16x16x32_bf16(a0, b0, acc00, 0, 0, 0);
        acc01 = __builtin_amdgcn_mfma_f32_16x16x32_bf16(a0, b1, acc01, 0, 0, 0);
        acc10 = __builtin_amdgcn_mfma_f32_16x16x32_bf16(a1, b0, acc10, 0, 0, 0);
        acc11 = __builtin_amdgcn_mfma_f32_16x16x32_bf16(a1, b1, acc11, 0, 0, 0);
    }
    const int c0 = w * 32 + m, c1 = c0 + 16;
    {
        const float g0 = bng[c0] * BN_SCALE, g1 = bng[c1] * BN_SCALE;
        const float bb0 = bnb[c0], bb1 = bnb[c1];
        const float al = a3[0];
        #pragma unroll
        for (int rt = 0; rt < 2; ++rt) {
            v4f A0 = rt ? acc10 : acc00;
            v4f A1 = rt ? acc11 : acc01;
            #pragma unroll
            for (int i = 0; i < 4; ++i) {
                const int r = rt * 16 + q * 4 + i;
                const int lab = sLab[r];
                float y0 = (A0[i] + E[lab * HD + c0]) * g0 + bb0;
                float y1 = (A1[i] + E[lab * HD + c1]) * g1 + bb1;
                y0 = (y0 >= 0.f) ? y0 : al * y0;
                y1 = (y1 >= 0.f) ? y1 : al * y1;
                sT[r * 136 + c0] = f2bf(y0);
                sT[r * 136 + c1] = f2bf(y1);
            }
        }
    }
    __syncthreads();

    v4f d00 = {0.f,0.f,0.f,0.f}, d01 = d00, d10 = d00, d11 = d00, e0 = d00, e1 = d00;
    #pragma unroll
    for (int kc = 0; kc < 4; ++kc) {
        v8s a0 = *(const v8s*)(sT + m * 136 + kc * 32 + q * 8);
        v8s a1 = *(const v8s*)(sT + (16 + m) * 136 + kc * 32 + q * 8);
        v8s b0 = *(const v8s*)(W3f + ((size_t)((nt0 * 4 + kc) * 64 + lane)) * 8);
        v8s b1 = *(const v8s*)(W3f + ((size_t)((nt1 * 4 + kc) * 64 + lane)) * 8);
        d00 = __builtin_amdgcn_mfma_f32_16x16x32_bf16(a0, b0, d00, 0, 0, 0);
        d01 = __builtin_amdgcn_mfma_f32_16x16x32_bf16(a0, b1, d01, 0, 0, 0);
        d10 = __builtin_amdgcn_mfma_f32_16x16x32_bf16(a1, b0, d10, 0, 0, 0);
        d11 = __builtin_amdgcn_mfma_f32_16x16x32_bf16(a1, b1, d11, 0, 0, 0);
        if (w == 3) {
            v8s b2 = *(const v8s*)(W3f + ((size_t)((8 * 4 + kc) * 64 + lane)) * 8);
            e0 = __builtin_amdgcn_mfma_f32_16x16x32_bf16(a0, b2, e0, 0, 0, 0);
            e1 = __builtin_amdgcn_mfma_f32_16x16x32_bf16(a1, b2, e1, 0, 0, 0);
        }
    }
    const float b30 = b3[c0], b31 = b3[c1];
    #pragma unroll
    for (int rt = 0; rt < 2; ++rt) {
        v4f D0 = rt ? d10 : d00;
        v4f D1 = rt ? d11 : d01;
        #pragma unroll
        for (int i = 0; i < 4; ++i) {
            const int r = row0 + rt * 16 + q * 4 + i;
            h[(size_t)r * F_IN + c0] = feat[(size_t)r * F_IN + c0] + D0[i] + b30;
            h[(size_t)r * F_IN + c1] = feat[(size_t)r * F_IN + c1] + D1[i] + b31;
        }
    }
    if (w == 3) {
        const int c2 = 128 + m;
        if (c2 < F_IN) {
            const float b32 = b3[c2];
            #pragma unroll
            for (int i = 0; i < 4; ++i) {
                const int ra = row0 + q * 4 + i;
                const int rb = ra + 16;
                h[(size_t)ra * F_IN + c2] = feat[(size_t)ra * F_IN + c2] + e0[i] + b32;
                h[(size_t)rb * F_IN + c2] = feat[(size_t)rb * F_IN + c2] + e1[i] + b32;
            }
        }
    }
}

// ---------------- kC4: all 4 projections in one block [R9-proven] ----------------
template<int K, int LDSK, int KC>
__global__ __launch_bounds__(256) void kC4_mf(const float* __restrict__ A,
        const short* __restrict__ WfBase,
        const float* __restrict__ bq, const float* __restrict__ bk,
        const float* __restrict__ bv, const float* __restrict__ bs,
        unsigned short* __restrict__ qh, unsigned short* __restrict__ kh,
        unsigned short* __restrict__ vh, float* __restrict__ sOut) {
    __shared__ float4 sAv[32 * LDSK / 4];
    float* sA = (float*)sAv;
    const int tid = threadIdx.x;
    const int row0 = blockIdx.x * 32;
    for (int idx = tid; idx < 32 * K; idx += 256) {
        int r = idx / K, c = idx - r * K;
        sA[r * LDSK + c] = A[(size_t)(row0 + r) * K + c];
    }
    if (K < KC * 32) {
        const int ZC = KC * 32 - K;
        for (int idx = tid; idx < 32 * ZC; idx += 256) {
            int r = idx / ZC, c = idx - r * ZC;
            sA[r * LDSK + K + c] = 0.f;
        }
    }
    __syncthreads();

    const int lane = tid & 63, w = tid >> 6;
    const int m = lane & 15, q = lane >> 4;
    const int nt0 = w * 2, nt1 = nt0 + 1;

    v8s afr0[KC], afr1[KC];
    #pragma unroll
    for (int kc = 0; kc < KC; ++kc) {
        const float* r0 = sA + m * LDSK + kc * 32 + q * 8;
        const float* r1 = sA + (16 + m) * LDSK + kc * 32 + q * 8;
        afr0[kc] = pack8(*(const float4*)r0, *(const float4*)(r0 + 4));
        afr1[kc] = pack8(*(const float4*)r1, *(const float4*)(r1 + 4));
    }

    const int c0 = w * 32 + m, c1 = c0 + 16;
    #pragma unroll
    for (int mat = 0; mat < 4; ++mat) {
        const short* Wf = WfBase + (size_t)mat * (KC * 4096);
        const float* bias = (mat == 0) ? bq : (mat == 1) ? bk : (mat == 2) ? bv : bs;
        v4f acc00 = {0.f,0.f,0.f,0.f}, acc01 = acc00, acc10 = acc00, acc11 = acc00;
        #pragma unroll
        for (int kc = 0; kc < KC; ++kc) {
            v8s b0 = *(const v8s*)(Wf + ((size_t)((nt0 * KC + kc) * 64 + lane)) * 8);
            v8s b1 = *(const v8s*)(Wf + ((size_t)((nt1 * KC + kc) * 64 + lane)) * 8);
            acc00 = __builtin_amdgcn_mfma_f32_16x16x32_bf16(afr0[kc], b0, acc00, 0, 0, 0);
            acc01 = __builtin_amdgcn_mfma_f32_16x16x32_bf16(afr0[kc], b1, acc01, 0, 0, 0);
            acc10 = __builtin_amdgcn_mfma_f32_16x16x32_bf16(afr1[kc], b0, acc10, 0, 0, 0);
            acc11 = __builtin_amdgcn_mfma_f32_16x16x32_bf16(afr1[kc], b1, acc11, 0, 0, 0);
        }
        const float b0v = bias[c0], b1v = bias[c1];
        if (mat < 3) {
            unsigned short* outh = (mat == 0) ? qh : (mat == 1) ? kh : vh;
            unsigned short* outw = outh + ((size_t)w * N_NODES + row0) * DHEAD;
            #pragma unroll
            for (int rt = 0; rt < 2; ++rt) {
                v4f A0 = rt ? acc10 : acc00;
                v4f A1 = rt ? acc11 : acc01;
                #pragma unroll
                for (int i = 0; i < 4; ++i) {
                    const int r = rt * 16 + q * 4 + i;
                    outw[(size_t)r * DHEAD + m]      = f2bf(A0[i] + b0v);
                    outw[(size_t)r * DHEAD + 16 + m] = f2bf(A1[i] + b1v);
                }
            }
        } else {
            #pragma unroll
            for (int rt = 0; rt < 2; ++rt) {
                v4f A0 = rt ? acc10 : acc00;
                v4f A1 = rt ? acc11 : acc01;
                #pragma unroll
                for (int i = 0; i < 4; ++i) {
                    const int r = rt * 16 + q * 4 + i;
                    sOut[(size_t)(row0 + r) * HD + c0] = A0[i] + b0v;
                    sOut[(size_t)(row0 + r) * HD + c1] = A1[i] + b1v;
                }
            }
        }
    }
}

// ---------------- kD: head-split attention, bf16 gathers [R9-proven] ----------------
__global__ __launch_bounds__(256) void kD_h(const unsigned short* __restrict__ qh,
        const unsigned short* __restrict__ kh, const unsigned short* __restrict__ vh,
        const int* __restrict__ esrc, float* __restrict__ agg) {
    __shared__ float sk[8][DHEAD];
    __shared__ int ssrc[8][DEG];
    __shared__ float sa[8][DEG];
    const int h = blockIdx.y;
    const int n0 = blockIdx.x * 8;
    const int t = threadIdx.x;
    const int j = t >> 5, e = t & 31;

    ssrc[j][e] = esrc[n0 * DEG + t];
    if (t < 128) {
        unsigned u = *((const unsigned*)(kh + ((size_t)h * N_NODES + n0) * DHEAD) + t);
        float* skf = &sk[0][0];
        skf[2 * t]     = bflo(u);
        skf[2 * t + 1] = bfhi(u);
    }
    __syncthreads();

    const int src = ssrc[j][e];
    const uint4* qp = (const uint4*)(qh + ((size_t)h * N_NODES + src) * DHEAD);
    const float* kj = sk[j];
    float sc = 0.f;
    #pragma unroll
    for (int i = 0; i < 4; ++i) {
        uint4 u = qp[i];
        sc = fmaf(bflo(u.x), kj[i * 8 + 0], sc);
        sc = fmaf(bfhi(u.x), kj[i * 8 + 1], sc);
        sc = fmaf(bflo(u.y), kj[i * 8 + 2], sc);
        sc = fmaf(bfhi(u.y), kj[i * 8 + 3], sc);
        sc = fmaf(bflo(u.z), kj[i * 8 + 4], sc);
        sc = fmaf(bfhi(u.z), kj[i * 8 + 5], sc);
        sc = fmaf(bflo(u.w), kj[i * 8 + 6], sc);
        sc = fmaf(bfhi(u.w), kj[i * 8 + 7], sc);
    }
    sc *= INV_SQRT_D;
    float m = sc;
    #pragma unroll
    for (int off = 16; off > 0; off >>= 1)
        m = fmaxf(m, __shfl_xor(m, off, 32));
    float p = expf(sc - m);
    float ssum = p;
    #pragma unroll
    for (int off = 16; off > 0; off >>= 1)
        ssum += __shfl_xor(ssum, off, 32);
    sa[j][e] = p / ssum;
    __syncthreads();

    const int d = t & 31;
    const unsigned short* vbase = vh + (size_t)h * N_NODES * DHEAD + d;
    float acc = 0.f;
    #pragma unroll
    for (int e2 = 0; e2 < DEG; ++e2) {
        const int s2 = ssrc[j][e2];
        acc = fmaf(bf2f(vbase[(size_t)s2 * DHEAD]), sa[j][e2], acc);
    }
    agg[(size_t)(n0 + j) * HD + h * DHEAD + d] = acc;
}

// ---------------- fast 128-thread block reduce [proven] ----------------
__device__ __forceinline__ float blockSum128(float v, float* s2, int tid) {
    #pragma unroll
    for (int o = 32; o > 0; o >>= 1) v += __shfl_xor(v, o, 64);
    if ((tid & 63) == 0) s2[tid >> 6] = v;
    __syncthreads();
    float r = s2[0] + s2[1];
    __syncthreads();
    return r;
}

// ---------------- kE: gate + gated mix + LayerNorm + PReLU, fp32 [proven] ----------------
__global__ void kE(const float* __restrict__ skip, const float* __restrict__ agg,
                   const float* __restrict__ Wg, const float* __restrict__ bg,
                   const float* __restrict__ lng, const float* __restrict__ lnb,
                   const float* __restrict__ ac,
                   float* __restrict__ hout) {
    __shared__ float red[2];
    int n = blockIdx.x, c = threadIdx.x;
    float sk = skip[n * HD + c], ag = agg[n * HD + c];
    float part = sk * Wg[c] + ag * Wg[HD + c] + (sk - ag) * Wg[2 * HD + c];
    float z = blockSum128(part, red, c) + bg[0];
    float g = 1.f / (1.f + expf(-z));
    float r = g * sk + (1.f - g) * ag;
    float mean = blockSum128(r, red, c) * (1.f / HD);
    float dv = r - mean;
    float var = blockSum128(dv * dv, red, c) * (1.f / HD);
    float y = dv * rsqrtf(var + 1e-5f) * lng[c] + lnb[c];
    float a = ac[0];
    hout[n * HD + c] = (y >= 0.f) ? y : a * y;
}

// ---------------- kF (MFMA, raceless LDS epilogue) [R9-proven] ----------------
__global__ __launch_bounds__(256) void kF_mf2(const float* __restrict__ A,
        const short* __restrict__ W4f, const float* __restrict__ b4,
        const float* __restrict__ bng, const float* __restrict__ bnb,
        const float* __restrict__ a5, const float* __restrict__ W5,
        const float* __restrict__ b5, float* __restrict__ out) {
    __shared__ float4 sAv[32 * 132 / 4];
    float* sA = (float*)sAv;
    const int tid = threadIdx.x;
    const int row0 = blockIdx.x * 32;
    for (int idx = tid; idx < 32 * HD; idx += 256) {
        int r = idx >> 7, c = idx & 127;
        sA[r * 132 + c] = A[(size_t)(row0 + r) * HD + c];
    }
    __syncthreads();
    const int lane = tid & 63, w = tid >> 6;
    const int m = lane & 15, q = lane >> 4;
    const int nt0 = w * 2, nt1 = nt0 + 1;
    v4f acc00 = {0.f,0.f,0.f,0.f}, acc01 = acc00, acc10 = acc00, acc11 = acc00;
    #pragma unroll
    for (int kc = 0; kc < 4; ++kc) {
        const float* r0 = sA + m * 132 + kc * 32 + q * 8;
        const float* r1 = sA + (16 + m) * 132 + kc * 32 + q * 8;
        v8s a0 = pack8(*(const float4*)r0, *(const float4*)(r0 + 4));
        v8s a1 = pack8(*(const float4*)r1, *(const float4*)(r1 + 4));
        v8s b0 = *(const v8s*)(W4f + ((size_t)((nt0 * 4 + kc) * 64 + lane)) * 8);
        v8s b1 = *(const v8s*)(W4f + ((size_t)((nt1 * 4 + kc) * 64 + lane)) * 8);
        acc00 = __builtin_amdgcn_mfma_f32_16x16x32_bf16(a0, b0, acc00, 0, 0, 0);
        acc01 = __builtin_amdgcn_mfma_f32_16x16x32_bf16(a0, b1, acc01, 0, 0, 0);
        acc10 = __builtin_amdgcn_mfma_f32_16x16x32_bf16(a1, b0, acc10, 0, 0, 0);
        acc11 = __builtin_amdgcn_mfma_f32_16x16x32_bf16(a1, b1, acc11, 0, 0, 0);
    }
    __syncthreads();
    const int c0 = w * 32 + m, c1 = c0 + 16;
    const float g0 = bng[c0] * BN_SCALE, g1 = bng[c1] * BN_SCALE;
    const float bb0 = bnb[c0], bb1 = bnb[c1];
    const float b40 = b4[c0], b41 = b4[c1];
    const float al = a5[0];
    #pragma unroll
    for (int rt = 0; rt < 2; ++rt) {
        v4f A0 = rt ? acc10 : acc00;
        v4f A1 = rt ? acc11 : acc01;
        #pragma unroll
        for (int i = 0; i < 4; ++i) {
            const int r = rt * 16 + q * 4 + i;
            float y0 = (A0[i] + b40) * g0 + bb0;
            float y1 = (A1[i] + b41) * g1 + bb1;
            y0 = (y0 >= 0.f) ? y0 : al * y0;
            y1 = (y1 >= 0.f) ? y1 : al * y1;
            sA[r * 132 + c0] = y0;
            sA[r * 132 + c1] = y1;
        }
    }
    __syncthreads();
    if (tid < 64) {
        const int r = tid >> 1, cls = tid & 1;
        const float* yr = sA + r * 132;
        float s = b5[cls];
        #pragma unroll 8
        for (int c = 0; c < HD; ++c)
            s = fmaf(yr[c], W5[c * 2 + cls], s);
        out[(size_t)(row0 + r) * N_CLS + cls] = s;
    }
}

extern "C" void kernel_launch(void* const* d_in, const int* in_sizes, int n_in,
                              void* d_out, int out_size, void* d_ws, size_t ws_size,
                              hipStream_t stream) {
    const float* feat  = (const float*)d_in[0];
    const float* lemb  = (const float*)d_in[1];
    const float* W1    = (const float*)d_in[2];
    const float* b1    = (const float*)d_in[3];
    const float* W2    = (const float*)d_in[4];
    const float* b2    = (const float*)d_in[5];
    const float* bn0g  = (const float*)d_in[6];
    const float* bn0b  = (const float*)d_in[7];
    const float* a3    = (const float*)d_in[8];
    const float* W3    = (const float*)d_in[9];
    const float* b3    = (const float*)d_in[10];
    const float* aconv = (const float*)d_in[35];
    const float* W4    = (const float*)d_in[36];
    const float* b4    = (const float*)d_in[37];
    const float* bn1g  = (const float*)d_in[38];
    const float* bn1b  = (const float*)d_in[39];
    const float* a5    = (const float*)d_in[40];
    const float* W5    = (const float*)d_in[41];
    const float* b5    = (const float*)d_in[42];
    const int*   labels = (const int*)d_in[43];
    const int*   esrc   = (const int*)d_in[44];

    char* ws = (char*)d_ws;
    float* bh  = (float*)ws;                       ws += sizeof(float) * N_NODES * F_IN;
    float* bs  = (float*)ws;                       ws += sizeof(float) * N_NODES * HD;
    float* bag = (float*)ws;                       ws += sizeof(float) * N_NODES * HD;
    float* bh2 = (float*)ws;                       ws += sizeof(float) * N_NODES * HD;
    unsigned short* bqh = (unsigned short*)ws;     ws += sizeof(short) * N_NODES * HD;
    unsigned short* bkh = (unsigned short*)ws;     ws += sizeof(short) * N_NODES * HD;
    unsigned short* bvh = (unsigned short*)ws;     ws += sizeof(short) * N_NODES * HD;
    short* Wf142 = (short*)ws;                     ws += sizeof(short) * 5 * 20480;  // W1,q0,k0,v0,s0
    short* Wf128 = (short*)ws;                     ws += sizeof(short) * 5 * 16384;  // q1,k1,v1,s1,W4
    short* W3f = (short*)ws;                       ws += sizeof(short) * 36 * 512;   // W3
    float* bE  = (float*)ws;                       ws += sizeof(float) * 3 * HD;     // E table
    float* out = (float*)d_out;

    dim3 gT(N_NODES / 32);
    dim3 gD(N_NODES / 8, NHEAD);

    // single fused prep launch: all swizzles + E table
    kPrep<<<dim3(201), 128, 0, stream>>>(
        W1, (const float*)d_in[11], (const float*)d_in[13],
        (const float*)d_in[15], (const float*)d_in[17],
        (const float*)d_in[23], (const float*)d_in[25],
        (const float*)d_in[27], (const float*)d_in[29], W4,
        W3, lemb, W2, b1, b2,
        Wf142, Wf128, W3f, bE);

    kAB_m<<<gT, 256, 0, stream>>>(feat, Wf142, W3f, labels, bE, bn0g, bn0b, a3, b3, bh);

    // conv layer 0 (K=142 -> LDSK=164, KC=5; projection weights at slots 1..4)
    kC4_mf<F_IN, 164, 5><<<gT, 256, 0, stream>>>(bh, Wf142 + 20480,
        (const float*)d_in[12], (const float*)d_in[14],
        (const float*)d_in[16], (const float*)d_in[18],
        bqh, bkh, bvh, bs);
    kD_h<<<gD, 256, 0, stream>>>(bqh, bkh, bvh, esrc, bag);
    kE<<<dim3(N_NODES), HD, 0, stream>>>(bs, bag, (const float*)d_in[19], (const float*)d_in[20],
        (const float*)d_in[21], (const float*)d_in[22], aconv, bh2);

    // conv layer 1 (K=128 -> LDSK=132, KC=4; projection weights at slots 0..3)
    kC4_mf<HD, 132, 4><<<gT, 256, 0, stream>>>(bh2, Wf128,
        (const float*)d_in[24], (const float*)d_in[26],
        (const float*)d_in[28], (const float*)d_in[30],
        bqh, bkh, bvh, bs);
    kD_h<<<gD, 256, 0, stream>>>(bqh, bkh, bvh, esrc, bag);
    kE<<<dim3(N_NODES), HD, 0, stream>>>(bs, bag, (const float*)d_in[31], (const float*)d_in[32],
        (const float*)d_in[33], (const float*)d_in[34], aconv, bh2);

    kF_mf2<<<gT, 256, 0, stream>>>(bh2, Wf128 + 4 * 16384, b4, bn1g, bn1b, a5, W5, b5, out);
}

// Round 13
// 280.721 us; speedup vs baseline: 1.7084x; 1.1175x over previous
//
#include <hip/hip_runtime.h>
#include <math.h>

#define N_NODES 20000
#define DEG 32
#define F_IN 142
#define HD 128
#define NHEAD 4
#define DHEAD 32
#define N_CLS 2

#define BN_SCALE 0.9999950000374997f
#define INV_SQRT_D 0.17677669529663687f

typedef short v8s __attribute__((ext_vector_type(8)));
typedef float v4f __attribute__((ext_vector_type(4)));

// ---- bf16 helpers (manual, RNE) ----
__device__ __forceinline__ unsigned short f2bf(float f) {
    unsigned u = __float_as_uint(f);
    return (unsigned short)((u + 0x7fffu + ((u >> 16) & 1u)) >> 16);
}
__device__ __forceinline__ unsigned pack2bf(float a, float b) {
    return (unsigned)f2bf(a) | ((unsigned)f2bf(b) << 16);
}
__device__ __forceinline__ float bf2f(unsigned short s) {
    return __uint_as_float((unsigned)s << 16);
}
__device__ __forceinline__ float bflo(unsigned u) { return __uint_as_float(u << 16); }
__device__ __forceinline__ float bfhi(unsigned u) { return __uint_as_float(u & 0xffff0000u); }

__device__ __forceinline__ v8s pack8(float4 f0, float4 f1) {
    union { v8s s; unsigned u[4]; } x;
    x.u[0] = pack2bf(f0.x, f0.y);
    x.u[1] = pack2bf(f0.z, f0.w);
    x.u[2] = pack2bf(f1.x, f1.y);
    x.u[3] = pack2bf(f1.z, f1.w);
    return x.s;
}

// ---- swizzle helper (proven): one tile of one matrix ----
__device__ __forceinline__ void swizTile(const float* __restrict__ W, int K, int KC,
                                         int tile, int L, short* __restrict__ outBase) {
    const int kc = tile % KC, nt = tile / KC;
    const int n = nt * 16 + (L & 15);
    const int kb = kc * 32 + (L >> 4) * 8;
    short v[8] __attribute__((aligned(16)));
    #pragma unroll
    for (int j = 0; j < 8; ++j) {
        int k = kb + j;
        v[j] = (k < K) ? (short)f2bf(W[(size_t)k * HD + n]) : (short)0;
    }
    *(uint4*)(outBase + ((size_t)tile * 64 + L) * 8) = *(const uint4*)v;
}

// ---------------- kPrep: ALL weight prep in one launch [R12-proven] ----------------
__global__ __launch_bounds__(128) void kPrep(
        const float* W142a, const float* W142b, const float* W142c,
        const float* W142d, const float* W142e,
        const float* W128a, const float* W128b, const float* W128c,
        const float* W128d, const float* W128e,
        const float* __restrict__ W3,
        const float* __restrict__ lemb, const float* __restrict__ W2,
        const float* __restrict__ b1, const float* __restrict__ b2,
        short* __restrict__ Wf142, short* __restrict__ Wf128,
        short* __restrict__ W3f, float* __restrict__ E) {
    const int b = blockIdx.x;
    const int t = threadIdx.x;
    if (b < 100) {
        const float* Wt[5] = {W142a, W142b, W142c, W142d, W142e};
        const int idx = b * 2 + (t >> 6);
        const int mat = idx / 40, tile = idx - mat * 40;
        swizTile(Wt[mat], F_IN, 5, tile, t & 63, Wf142 + (size_t)mat * 20480);
    } else if (b < 180) {
        const float* Wt[5] = {W128a, W128b, W128c, W128d, W128e};
        const int idx = (b - 100) * 2 + (t >> 6);
        const int mat = idx >> 5, tile = idx & 31;
        swizTile(Wt[mat], HD, 4, tile, t & 63, Wf128 + (size_t)mat * 16384);
    } else if (b < 198) {
        const int tile = (b - 180) * 2 + (t >> 6);
        const int kc = tile & 3, nt = tile >> 2;
        const int L = t & 63;
        const int n = nt * 16 + (L & 15);
        const int kb = kc * 32 + (L >> 4) * 8;
        short v[8] __attribute__((aligned(16)));
        #pragma unroll
        for (int j = 0; j < 8; ++j)
            v[j] = (n < F_IN) ? (short)f2bf(W3[(size_t)(kb + j) * F_IN + n]) : (short)0;
        *(uint4*)(W3f + ((size_t)tile * 64 + L) * 8) = *(const uint4*)v;
    } else {
        __shared__ float sl[F_IN];
        const int l = b - 198;
        for (int f = t; f < F_IN; f += 128) sl[f] = lemb[l * F_IN + f];
        __syncthreads();
        float acc = b1[t] + b2[t];
        for (int f = 0; f < F_IN; ++f) acc += sl[f] * W2[f * HD + t];
        E[l * HD + t] = acc;
    }
}

// ---------------- kABC: kAB + layer-0 projections fused (h never leaves LDS) ----------------
__global__ __launch_bounds__(256) void kABC(const float* __restrict__ feat,
        const short* __restrict__ Wf142, const short* __restrict__ W3f,
        const int* __restrict__ labels, const float* __restrict__ E,
        const float* __restrict__ bng, const float* __restrict__ bnb,
        const float* __restrict__ a3, const float* __restrict__ b3,
        const float* __restrict__ bq, const float* __restrict__ bk,
        const float* __restrict__ bv, const float* __restrict__ bsb,
        unsigned short* __restrict__ qh, unsigned short* __restrict__ kh,
        unsigned short* __restrict__ vh, float* __restrict__ sOut) {
    __shared__ float4 sAv[32 * 164 / 4];   // feat fp32, stride 164
    __shared__ uint4  sTv[32 * 136 / 8];   // t bf16, stride 136
    __shared__ uint4  sHv[32 * 168 / 8];   // h bf16, stride 168 (K padded to 160)
    __shared__ int sLab[32];
    float* sA = (float*)sAv;
    unsigned short* sT = (unsigned short*)sTv;
    unsigned short* sH = (unsigned short*)sHv;
    const int tid = threadIdx.x;
    const int row0 = blockIdx.x * 32;
    for (int idx = tid; idx < 32 * F_IN; idx += 256) {
        int r = idx / F_IN, c = idx - r * F_IN;
        sA[r * 164 + c] = feat[(size_t)(row0 + r) * F_IN + c];
    }
    {   const int ZC = 160 - F_IN;
        for (int idx = tid; idx < 32 * ZC; idx += 256) {
            int r = idx / ZC, c = idx - r * ZC;
            sA[r * 164 + F_IN + c] = 0.f;
        }
    }
    if (tid < 32) sLab[tid] = labels[row0 + tid];
    __syncthreads();

    const int lane = tid & 63, w = tid >> 6;
    const int m = lane & 15, q = lane >> 4;
    const int nt0 = w * 2, nt1 = nt0 + 1;
    const int c0 = w * 32 + m, c1 = c0 + 16;

    // ---- phase 1: t = PReLU(BN(feat @ W1 + E[lab])) -> sT bf16 [proven kAB body] ----
    {
        v4f acc00 = {0.f,0.f,0.f,0.f}, acc01 = acc00, acc10 = acc00, acc11 = acc00;
        #pragma unroll
        for (int kc = 0; kc < 5; ++kc) {
            const float* r0 = sA + m * 164 + kc * 32 + q * 8;
            const float* r1 = sA + (16 + m) * 164 + kc * 32 + q * 8;
            v8s a0 = pack8(*(const float4*)r0, *(const float4*)(r0 + 4));
            v8s a1 = pack8(*(const float4*)r1, *(const float4*)(r1 + 4));
            v8s b0 = *(const v8s*)(Wf142 + ((size_t)((nt0 * 5 + kc) * 64 + lane)) * 8);
            v8s b1 = *(const v8s*)(Wf142 + ((size_t)((nt1 * 5 + kc) * 64 + lane)) * 8);
            acc00 = __builtin_amdgcn_mfma_f32_16x16x32_bf16(a0, b0, acc00, 0, 0, 0);
            acc01 = __builtin_amdgcn_mfma_f32_16x16x32_bf16(a0, b1, acc01, 0, 0, 0);
            acc10 = __builtin_amdgcn_mfma_f32_16x16x32_bf16(a1, b0, acc10, 0, 0, 0);
            acc11 = __builtin_amdgcn_mfma_f32_16x16x32_bf16(a1, b1, acc11, 0, 0, 0);
        }
        const float g0 = bng[c0] * BN_SCALE, g1 = bng[c1] * BN_SCALE;
        const float bb0 = bnb[c0], bb1 = bnb[c1];
        const float al = a3[0];
        #pragma unroll
        for (int rt = 0; rt < 2; ++rt) {
            v4f A0 = rt ? acc10 : acc00;
            v4f A1 = rt ? acc11 : acc01;
            #pragma unroll
            for (int i = 0; i < 4; ++i) {
                const int r = rt * 16 + q * 4 + i;
                const int lab = sLab[r];
                float y0 = (A0[i] + E[lab * HD + c0]) * g0 + bb0;
                float y1 = (A1[i] + E[lab * HD + c1]) * g1 + bb1;
                y0 = (y0 >= 0.f) ? y0 : al * y0;
                y1 = (y1 >= 0.f) ? y1 : al * y1;
                sT[r * 136 + c0] = f2bf(y0);
                sT[r * 136 + c1] = f2bf(y1);
            }
        }
    }
    __syncthreads();

    // ---- phase 2: h = feat + t @ W3 + b3 -> sH bf16 [proven kAB body, LDS sink] ----
    {
        v4f d00 = {0.f,0.f,0.f,0.f}, d01 = d00, d10 = d00, d11 = d00, e0 = d00, e1 = d00;
        #pragma unroll
        for (int kc = 0; kc < 4; ++kc) {
            v8s a0 = *(const v8s*)(sT + m * 136 + kc * 32 + q * 8);
            v8s a1 = *(const v8s*)(sT + (16 + m) * 136 + kc * 32 + q * 8);
            v8s b0 = *(const v8s*)(W3f + ((size_t)((nt0 * 4 + kc) * 64 + lane)) * 8);
            v8s b1 = *(const v8s*)(W3f + ((size_t)((nt1 * 4 + kc) * 64 + lane)) * 8);
            d00 = __builtin_amdgcn_mfma_f32_16x16x32_bf16(a0, b0, d00, 0, 0, 0);
            d01 = __builtin_amdgcn_mfma_f32_16x16x32_bf16(a0, b1, d01, 0, 0, 0);
            d10 = __builtin_amdgcn_mfma_f32_16x16x32_bf16(a1, b0, d10, 0, 0, 0);
            d11 = __builtin_amdgcn_mfma_f32_16x16x32_bf16(a1, b1, d11, 0, 0, 0);
            if (w == 3) {
                v8s b2 = *(const v8s*)(W3f + ((size_t)((8 * 4 + kc) * 64 + lane)) * 8);
                e0 = __builtin_amdgcn_mfma_f32_16x16x32_bf16(a0, b2, e0, 0, 0, 0);
                e1 = __builtin_amdgcn_mfma_f32_16x16x32_bf16(a1, b2, e1, 0, 0, 0);
            }
        }
        const float b30 = b3[c0], b31 = b3[c1];
        #pragma unroll
        for (int rt = 0; rt < 2; ++rt) {
            v4f D0 = rt ? d10 : d00;
            v4f D1 = rt ? d11 : d01;
            #pragma unroll
            for (int i = 0; i < 4; ++i) {
                const int r = rt * 16 + q * 4 + i;
                sH[r * 168 + c0] = f2bf(sA[r * 164 + c0] + D0[i] + b30);
                sH[r * 168 + c1] = f2bf(sA[r * 164 + c1] + D1[i] + b31);
            }
        }
        if (w == 3) {
            const int c2 = 128 + m;
            const bool ok = (c2 < F_IN);
            const float b32 = ok ? b3[c2] : 0.f;
            #pragma unroll
            for (int i = 0; i < 4; ++i) {
                const int ra = q * 4 + i;
                const int rb = ra + 16;
                sH[ra * 168 + c2] = ok ? f2bf(sA[ra * 164 + c2] + e0[i] + b32) : (unsigned short)0;
                sH[rb * 168 + c2] = ok ? f2bf(sA[rb * 164 + c2] + e1[i] + b32) : (unsigned short)0;
            }
        }
        // zero-fill k in [144,160): 32 rows x 8 uint pairs
        if (tid < 256) {
            const int r = tid >> 3, cp = tid & 7;
            ((unsigned*)sH)[r * 84 + 72 + cp] = 0u;
        }
    }
    __syncthreads();

    // ---- phase 3: 4 projections from sH [proven kC4 body; fragments are direct v8s reads] ----
    v8s afr0[5], afr1[5];
    #pragma unroll
    for (int kc = 0; kc < 5; ++kc) {
        afr0[kc] = *(const v8s*)(sH + m * 168 + kc * 32 + q * 8);
        afr1[kc] = *(const v8s*)(sH + (16 + m) * 168 + kc * 32 + q * 8);
    }
    #pragma unroll
    for (int mat = 0; mat < 4; ++mat) {
        const short* Wf = Wf142 + (size_t)(mat + 1) * 20480;   // slots 1..4
        const float* bias = (mat == 0) ? bq : (mat == 1) ? bk : (mat == 2) ? bv : bsb;
        v4f acc00 = {0.f,0.f,0.f,0.f}, acc01 = acc00, acc10 = acc00, acc11 = acc00;
        #pragma unroll
        for (int kc = 0; kc < 5; ++kc) {
            v8s b0 = *(const v8s*)(Wf + ((size_t)((nt0 * 5 + kc) * 64 + lane)) * 8);
            v8s b1 = *(const v8s*)(Wf + ((size_t)((nt1 * 5 + kc) * 64 + lane)) * 8);
            acc00 = __builtin_amdgcn_mfma_f32_16x16x32_bf16(afr0[kc], b0, acc00, 0, 0, 0);
            acc01 = __builtin_amdgcn_mfma_f32_16x16x32_bf16(afr0[kc], b1, acc01, 0, 0, 0);
            acc10 = __builtin_amdgcn_mfma_f32_16x16x32_bf16(afr1[kc], b0, acc10, 0, 0, 0);
            acc11 = __builtin_amdgcn_mfma_f32_16x16x32_bf16(afr1[kc], b1, acc11, 0, 0, 0);
        }
        const float b0v = bias[c0], b1v = bias[c1];
        if (mat < 3) {
            unsigned short* outh = (mat == 0) ? qh : (mat == 1) ? kh : vh;
            unsigned short* outw = outh + ((size_t)w * N_NODES + row0) * DHEAD;
            #pragma unroll
            for (int rt = 0; rt < 2; ++rt) {
                v4f A0 = rt ? acc10 : acc00;
                v4f A1 = rt ? acc11 : acc01;
                #pragma unroll
                for (int i = 0; i < 4; ++i) {
                    const int r = rt * 16 + q * 4 + i;
                    outw[(size_t)r * DHEAD + m]      = f2bf(A0[i] + b0v);
                    outw[(size_t)r * DHEAD + 16 + m] = f2bf(A1[i] + b1v);
                }
            }
        } else {
            #pragma unroll
            for (int rt = 0; rt < 2; ++rt) {
                v4f A0 = rt ? acc10 : acc00;
                v4f A1 = rt ? acc11 : acc01;
                #pragma unroll
                for (int i = 0; i < 4; ++i) {
                    const int r = rt * 16 + q * 4 + i;
                    sOut[(size_t)(row0 + r) * HD + c0] = A0[i] + b0v;
                    sOut[(size_t)(row0 + r) * HD + c1] = A1[i] + b1v;
                }
            }
        }
    }
}

// ---- fused kE phase: gate+LN+PReLU for 32 rows -> sA fp32 (stride 132) [proven kDE_h epilogue idiom] ----
__device__ __forceinline__ void kE_phase(const float* __restrict__ skip,
        const float* __restrict__ agg, const float* __restrict__ Wg,
        const float* __restrict__ bg, const float* __restrict__ lng,
        const float* __restrict__ lnb, const float* __restrict__ ac,
        float* sA, int row0, int t) {
    const int e = t & 31, g8 = t >> 5;
    const float al = ac[0];
    const float bg0 = bg[0];
    for (int ng = 0; ng < 4; ++ng) {
        const int j = ng * 8 + g8;
        const size_t n = (size_t)(row0 + j);
        float skv[4], agv[4];
        float part = 0.f;
        #pragma unroll
        for (int k2 = 0; k2 < 4; ++k2) {
            const int c = e + 32 * k2;
            skv[k2] = skip[n * HD + c];
            agv[k2] = agg[n * HD + c];
            part += skv[k2] * Wg[c] + agv[k2] * Wg[HD + c] + (skv[k2] - agv[k2]) * Wg[2 * HD + c];
        }
        #pragma unroll
        for (int off = 16; off > 0; off >>= 1)
            part += __shfl_xor(part, off, 32);
        const float g = 1.f / (1.f + expf(-(part + bg0)));
        float rv[4], rsum = 0.f;
        #pragma unroll
        for (int k2 = 0; k2 < 4; ++k2) {
            rv[k2] = g * skv[k2] + (1.f - g) * agv[k2];
            rsum += rv[k2];
        }
        #pragma unroll
        for (int off = 16; off > 0; off >>= 1)
            rsum += __shfl_xor(rsum, off, 32);
        const float mean = rsum * (1.f / HD);
        float dv[4], vsum = 0.f;
        #pragma unroll
        for (int k2 = 0; k2 < 4; ++k2) {
            dv[k2] = rv[k2] - mean;
            vsum += dv[k2] * dv[k2];
        }
        #pragma unroll
        for (int off = 16; off > 0; off >>= 1)
            vsum += __shfl_xor(vsum, off, 32);
        const float inv = rsqrtf(vsum * (1.f / HD) + 1e-5f);
        #pragma unroll
        for (int k2 = 0; k2 < 4; ++k2) {
            const int c = e + 32 * k2;
            float y = dv[k2] * inv * lng[c] + lnb[c];
            sA[j * 132 + c] = (y >= 0.f) ? y : al * y;
        }
    }
}

// ---------------- kEC4: layer-0 kE + layer-1 projections (x never leaves LDS) ----------------
__global__ __launch_bounds__(256) void kEC4(const float* __restrict__ skip,
        const float* __restrict__ agg,
        const float* __restrict__ Wg, const float* __restrict__ bg,
        const float* __restrict__ lng, const float* __restrict__ lnb,
        const float* __restrict__ ac,
        const short* __restrict__ Wf128,
        const float* __restrict__ bq, const float* __restrict__ bk,
        const float* __restrict__ bv, const float* __restrict__ bsb,
        unsigned short* __restrict__ qh, unsigned short* __restrict__ kh,
        unsigned short* __restrict__ vh, float* __restrict__ sOut) {
    __shared__ float4 sAv[32 * 132 / 4];
    float* sA = (float*)sAv;
    const int tid = threadIdx.x;
    const int row0 = blockIdx.x * 32;
    kE_phase(skip, agg, Wg, bg, lng, lnb, ac, sA, row0, tid);
    __syncthreads();

    const int lane = tid & 63, w = tid >> 6;
    const int m = lane & 15, q = lane >> 4;
    const int nt0 = w * 2, nt1 = nt0 + 1;
    v8s afr0[4], afr1[4];
    #pragma unroll
    for (int kc = 0; kc < 4; ++kc) {
        const float* r0 = sA + m * 132 + kc * 32 + q * 8;
        const float* r1 = sA + (16 + m) * 132 + kc * 32 + q * 8;
        afr0[kc] = pack8(*(const float4*)r0, *(const float4*)(r0 + 4));
        afr1[kc] = pack8(*(const float4*)r1, *(const float4*)(r1 + 4));
    }
    const int c0 = w * 32 + m, c1 = c0 + 16;
    #pragma unroll
    for (int mat = 0; mat < 4; ++mat) {
        const short* Wf = Wf128 + (size_t)mat * 16384;
        const float* bias = (mat == 0) ? bq : (mat == 1) ? bk : (mat == 2) ? bv : bsb;
        v4f acc00 = {0.f,0.f,0.f,0.f}, acc01 = acc00, acc10 = acc00, acc11 = acc00;
        #pragma unroll
        for (int kc = 0; kc < 4; ++kc) {
            v8s b0 = *(const v8s*)(Wf + ((size_t)((nt0 * 4 + kc) * 64 + lane)) * 8);
            v8s b1 = *(const v8s*)(Wf + ((size_t)((nt1 * 4 + kc) * 64 + lane)) * 8);
            acc00 = __builtin_amdgcn_mfma_f32_16x16x32_bf16(afr0[kc], b0, acc00, 0, 0, 0);
            acc01 = __builtin_amdgcn_mfma_f32_16x16x32_bf16(afr0[kc], b1, acc01, 0, 0, 0);
            acc10 = __builtin_amdgcn_mfma_f32_16x16x32_bf16(afr1[kc], b0, acc10, 0, 0, 0);
            acc11 = __builtin_amdgcn_mfma_f32_16x16x32_bf16(afr1[kc], b1, acc11, 0, 0, 0);
        }
        const float b0v = bias[c0], b1v = bias[c1];
        if (mat < 3) {
            unsigned short* outh = (mat == 0) ? qh : (mat == 1) ? kh : vh;
            unsigned short* outw = outh + ((size_t)w * N_NODES + row0) * DHEAD;
            #pragma unroll
            for (int rt = 0; rt < 2; ++rt) {
                v4f A0 = rt ? acc10 : acc00;
                v4f A1 = rt ? acc11 : acc01;
                #pragma unroll
                for (int i = 0; i < 4; ++i) {
                    const int r = rt * 16 + q * 4 + i;
                    outw[(size_t)r * DHEAD + m]      = f2bf(A0[i] + b0v);
                    outw[(size_t)r * DHEAD + 16 + m] = f2bf(A1[i] + b1v);
                }
            }
        } else {
            #pragma unroll
            for (int rt = 0; rt < 2; ++rt) {
                v4f A0 = rt ? acc10 : acc00;
                v4f A1 = rt ? acc11 : acc01;
                #pragma unroll
                for (int i = 0; i < 4; ++i) {
                    const int r = rt * 16 + q * 4 + i;
                    sOut[(size_t)(row0 + r) * HD + c0] = A0[i] + b0v;
                    sOut[(size_t)(row0 + r) * HD + c1] = A1[i] + b1v;
                }
            }
        }
    }
}

// ---------------- kD: head-split attention, bf16 gathers [proven, byte-identical] ----------------
__global__ __launch_bounds__(256) void kD_h(const unsigned short* __restrict__ qh,
        const unsigned short* __restrict__ kh, const unsigned short* __restrict__ vh,
        const int* __restrict__ esrc, float* __restrict__ agg) {
    __shared__ float sk[8][DHEAD];
    __shared__ int ssrc[8][DEG];
    __shared__ float sa[8][DEG];
    const int h = blockIdx.y;
    const int n0 = blockIdx.x * 8;
    const int t = threadIdx.x;
    const int j = t >> 5, e = t & 31;

    ssrc[j][e] = esrc[n0 * DEG + t];
    if (t < 128) {
        unsigned u = *((const unsigned*)(kh + ((size_t)h * N_NODES + n0) * DHEAD) + t);
        float* skf = &sk[0][0];
        skf[2 * t]     = bflo(u);
        skf[2 * t + 1] = bfhi(u);
    }
    __syncthreads();

    const int src = ssrc[j][e];
    const uint4* qp = (const uint4*)(qh + ((size_t)h * N_NODES + src) * DHEAD);
    const float* kj = sk[j];
    float sc = 0.f;
    #pragma unroll
    for (int i = 0; i < 4; ++i) {
        uint4 u = qp[i];
        sc = fmaf(bflo(u.x), kj[i * 8 + 0], sc);
        sc = fmaf(bfhi(u.x), kj[i * 8 + 1], sc);
        sc = fmaf(bflo(u.y), kj[i * 8 + 2], sc);
        sc = fmaf(bfhi(u.y), kj[i * 8 + 3], sc);
        sc = fmaf(bflo(u.z), kj[i * 8 + 4], sc);
        sc = fmaf(bfhi(u.z), kj[i * 8 + 5], sc);
        sc = fmaf(bflo(u.w), kj[i * 8 + 6], sc);
        sc = fmaf(bfhi(u.w), kj[i * 8 + 7], sc);
    }
    sc *= INV_SQRT_D;
    float m = sc;
    #pragma unroll
    for (int off = 16; off > 0; off >>= 1)
        m = fmaxf(m, __shfl_xor(m, off, 32));
    float p = expf(sc - m);
    float ssum = p;
    #pragma unroll
    for (int off = 16; off > 0; off >>= 1)
        ssum += __shfl_xor(ssum, off, 32);
    sa[j][e] = p / ssum;
    __syncthreads();

    const int d = t & 31;
    const unsigned short* vbase = vh + (size_t)h * N_NODES * DHEAD + d;
    float acc = 0.f;
    #pragma unroll
    for (int e2 = 0; e2 < DEG; ++e2) {
        const int s2 = ssrc[j][e2];
        acc = fmaf(bf2f(vbase[(size_t)s2 * DHEAD]), sa[j][e2], acc);
    }
    agg[(size_t)(n0 + j) * HD + h * DHEAD + d] = acc;
}

// ---------------- kEF: layer-1 kE + kF fused (x never leaves LDS) ----------------
__global__ __launch_bounds__(256) void kEF(const float* __restrict__ skip,
        const float* __restrict__ agg,
        const float* __restrict__ Wg, const float* __restrict__ bg,
        const float* __restrict__ lng, const float* __restrict__ lnb,
        const float* __restrict__ ac,
        const short* __restrict__ W4f, const float* __restrict__ b4,
        const float* __restrict__ bng, const float* __restrict__ bnb,
        const float* __restrict__ a5, const float* __restrict__ W5,
        const float* __restrict__ b5, float* __restrict__ out) {
    __shared__ float4 sAv[32 * 132 / 4];
    float* sA = (float*)sAv;
    const int tid = threadIdx.x;
    const int row0 = blockIdx.x * 32;
    kE_phase(skip, agg, Wg, bg, lng, lnb, ac, sA, row0, tid);
    __syncthreads();

    const int lane = tid & 63, w = tid >> 6;
    const int m = lane & 15, q = lane >> 4;
    const int nt0 = w * 2, nt1 = nt0 + 1;
    v4f acc00 = {0.f,0.f,0.f,0.f}, acc01 = acc00, acc10 = acc00, acc11 = acc00;
    #pragma unroll
    for (int kc = 0; kc < 4; ++kc) {
        const float* r0 = sA + m * 132 + kc * 32 + q * 8;
        const float* r1 = sA + (16 + m) * 132 + kc * 32 + q * 8;
        v8s a0 = pack8(*(const float4*)r0, *(const float4*)(r0 + 4));
        v8s a1 = pack8(*(const float4*)r1, *(const float4*)(r1 + 4));
        v8s b0 = *(const v8s*)(W4f + ((size_t)((nt0 * 4 + kc) * 64 + lane)) * 8);
        v8s b1 = *(const v8s*)(W4f + ((size_t)((nt1 * 4 + kc) * 64 + lane)) * 8);
        acc00 = __builtin_amdgcn_mfma_f32_16x16x32_bf16(a0, b0, acc00, 0, 0, 0);
        acc01 = __builtin_amdgcn_mfma_f32_16x16x32_bf16(a0, b1, acc01, 0, 0, 0);
        acc10 = __builtin_amdgcn_mfma_f32_16x16x32_bf16(a1, b0, acc10, 0, 0, 0);
        acc11 = __builtin_amdgcn_mfma_f32_16x16x32_bf16(a1, b1, acc11, 0, 0, 0);
    }
    __syncthreads();
    const int c0 = w * 32 + m, c1 = c0 + 16;
    const float g0 = bng[c0] * BN_SCALE, g1 = bng[c1] * BN_SCALE;
    const float bb0 = bnb[c0], bb1 = bnb[c1];
    const float b40 = b4[c0], b41 = b4[c1];
    const float al = a5[0];
    #pragma unroll
    for (int rt = 0; rt < 2; ++rt) {
        v4f A0 = rt ? acc10 : acc00;
        v4f A1 = rt ? acc11 : acc01;
        #pragma unroll
        for (int i = 0; i < 4; ++i) {
            const int r = rt * 16 + q * 4 + i;
            float y0 = (A0[i] + b40) * g0 + bb0;
            float y1 = (A1[i] + b41) * g1 + bb1;
            y0 = (y0 >= 0.f) ? y0 : al * y0;
            y1 = (y1 >= 0.f) ? y1 : al * y1;
            sA[r * 132 + c0] = y0;
            sA[r * 132 + c1] = y1;
        }
    }
    __syncthreads();
    if (tid < 64) {
        const int r = tid >> 1, cls = tid & 1;
        const float* yr = sA + r * 132;
        float s = b5[cls];
        #pragma unroll 8
        for (int c = 0; c < HD; ++c)
            s = fmaf(yr[c], W5[c * 2 + cls], s);
        out[(size_t)(row0 + r) * N_CLS + cls] = s;
    }
}

extern "C" void kernel_launch(void* const* d_in, const int* in_sizes, int n_in,
                              void* d_out, int out_size, void* d_ws, size_t ws_size,
                              hipStream_t stream) {
    const float* feat  = (const float*)d_in[0];
    const float* lemb  = (const float*)d_in[1];
    const float* W1    = (const float*)d_in[2];
    const float* b1    = (const float*)d_in[3];
    const float* W2    = (const float*)d_in[4];
    const float* b2    = (const float*)d_in[5];
    const float* bn0g  = (const float*)d_in[6];
    const float* bn0b  = (const float*)d_in[7];
    const float* a3    = (const float*)d_in[8];
    const float* W3    = (const float*)d_in[9];
    const float* b3    = (const float*)d_in[10];
    const float* aconv = (const float*)d_in[35];
    const float* W4    = (const float*)d_in[36];
    const float* b4    = (const float*)d_in[37];
    const float* bn1g  = (const float*)d_in[38];
    const float* bn1b  = (const float*)d_in[39];
    const float* a5    = (const float*)d_in[40];
    const float* W5    = (const float*)d_in[41];
    const float* b5    = (const float*)d_in[42];
    const int*   labels = (const int*)d_in[43];
    const int*   esrc   = (const int*)d_in[44];

    char* ws = (char*)d_ws;
    float* bs  = (float*)ws;                       ws += sizeof(float) * N_NODES * HD;
    float* bag = (float*)ws;                       ws += sizeof(float) * N_NODES * HD;
    unsigned short* bqh = (unsigned short*)ws;     ws += sizeof(short) * N_NODES * HD;
    unsigned short* bkh = (unsigned short*)ws;     ws += sizeof(short) * N_NODES * HD;
    unsigned short* bvh = (unsigned short*)ws;     ws += sizeof(short) * N_NODES * HD;
    short* Wf142 = (short*)ws;                     ws += sizeof(short) * 5 * 20480;  // W1,q0,k0,v0,s0
    short* Wf128 = (short*)ws;                     ws += sizeof(short) * 5 * 16384;  // q1,k1,v1,s1,W4
    short* W3f = (short*)ws;                       ws += sizeof(short) * 36 * 512;   // W3
    float* bE  = (float*)ws;                       ws += sizeof(float) * 3 * HD;     // E table
    float* out = (float*)d_out;

    dim3 gT(N_NODES / 32);
    dim3 gD(N_NODES / 8, NHEAD);

    kPrep<<<dim3(201), 128, 0, stream>>>(
        W1, (const float*)d_in[11], (const float*)d_in[13],
        (const float*)d_in[15], (const float*)d_in[17],
        (const float*)d_in[23], (const float*)d_in[25],
        (const float*)d_in[27], (const float*)d_in[29], W4,
        W3, lemb, W2, b1, b2,
        Wf142, Wf128, W3f, bE);

    // layer 0: kAB + projections fused
    kABC<<<gT, 256, 0, stream>>>(feat, Wf142, W3f, labels, bE, bn0g, bn0b, a3, b3,
        (const float*)d_in[12], (const float*)d_in[14],
        (const float*)d_in[16], (const float*)d_in[18],
        bqh, bkh, bvh, bs);
    kD_h<<<gD, 256, 0, stream>>>(bqh, bkh, bvh, esrc, bag);

    // layer 1: layer-0 kE + projections fused (bs overwritten in place, row-aligned)
    kEC4<<<gT, 256, 0, stream>>>(bs, bag,
        (const float*)d_in[19], (const float*)d_in[20],
        (const float*)d_in[21], (const float*)d_in[22], aconv,
        Wf128,
        (const float*)d_in[24], (const float*)d_in[26],
        (const float*)d_in[28], (const float*)d_in[30],
        bqh, bkh, bvh, bs);
    kD_h<<<gD, 256, 0, stream>>>(bqh, bkh, bvh, esrc, bag);

    // epilogue: layer-1 kE + kF fused
    kEF<<<gT, 256, 0, stream>>>(bs, bag,
        (const float*)d_in[31], (const float*)d_in[32],
        (const float*)d_in[33], (const float*)d_in[34], aconv,
        Wf128 + 4 * 16384, b4, bn1g, bn1b, a5, W5, b5, out);
}

// Round 14
// 273.361 us; speedup vs baseline: 1.7544x; 1.0269x over previous
//
#include <hip/hip_runtime.h>
#include <math.h>

#define N_NODES 20000
#define DEG 32
#define F_IN 142
#define HD 128
#define NHEAD 4
#define DHEAD 32
#define N_CLS 2

#define BN_SCALE 0.9999950000374997f
#define INV_SQRT_D 0.17677669529663687f

typedef short v8s __attribute__((ext_vector_type(8)));
typedef float v4f __attribute__((ext_vector_type(4)));

// ---- bf16 helpers (manual, RNE) ----
__device__ __forceinline__ unsigned short f2bf(float f) {
    unsigned u = __float_as_uint(f);
    return (unsigned short)((u + 0x7fffu + ((u >> 16) & 1u)) >> 16);
}
__device__ __forceinline__ unsigned pack2bf(float a, float b) {
    return (unsigned)f2bf(a) | ((unsigned)f2bf(b) << 16);
}
__device__ __forceinline__ float bf2f(unsigned short s) {
    return __uint_as_float((unsigned)s << 16);
}
__device__ __forceinline__ float bflo(unsigned u) { return __uint_as_float(u << 16); }
__device__ __forceinline__ float bfhi(unsigned u) { return __uint_as_float(u & 0xffff0000u); }

__device__ __forceinline__ v8s pack8(float4 f0, float4 f1) {
    union { v8s s; unsigned u[4]; } x;
    x.u[0] = pack2bf(f0.x, f0.y);
    x.u[1] = pack2bf(f0.z, f0.w);
    x.u[2] = pack2bf(f1.x, f1.y);
    x.u[3] = pack2bf(f1.z, f1.w);
    return x.s;
}

// ---- swizzle helper (proven): one tile of one matrix ----
__device__ __forceinline__ void swizTile(const float* __restrict__ W, int K, int KC,
                                         int tile, int L, short* __restrict__ outBase) {
    const int kc = tile % KC, nt = tile / KC;
    const int n = nt * 16 + (L & 15);
    const int kb = kc * 32 + (L >> 4) * 8;
    short v[8] __attribute__((aligned(16)));
    #pragma unroll
    for (int j = 0; j < 8; ++j) {
        int k = kb + j;
        v[j] = (k < K) ? (short)f2bf(W[(size_t)k * HD + n]) : (short)0;
    }
    *(uint4*)(outBase + ((size_t)tile * 64 + L) * 8) = *(const uint4*)v;
}

// ---------------- kPrep: ALL weight prep in one launch [proven] ----------------
__global__ __launch_bounds__(128) void kPrep(
        const float* W142a, const float* W142b, const float* W142c,
        const float* W142d, const float* W142e,
        const float* W128a, const float* W128b, const float* W128c,
        const float* W128d, const float* W128e,
        const float* __restrict__ W3,
        const float* __restrict__ lemb, const float* __restrict__ W2,
        const float* __restrict__ b1, const float* __restrict__ b2,
        short* __restrict__ Wf142, short* __restrict__ Wf128,
        short* __restrict__ W3f, float* __restrict__ E) {
    const int b = blockIdx.x;
    const int t = threadIdx.x;
    if (b < 100) {
        const float* Wt[5] = {W142a, W142b, W142c, W142d, W142e};
        const int idx = b * 2 + (t >> 6);
        const int mat = idx / 40, tile = idx - mat * 40;
        swizTile(Wt[mat], F_IN, 5, tile, t & 63, Wf142 + (size_t)mat * 20480);
    } else if (b < 180) {
        const float* Wt[5] = {W128a, W128b, W128c, W128d, W128e};
        const int idx = (b - 100) * 2 + (t >> 6);
        const int mat = idx >> 5, tile = idx & 31;
        swizTile(Wt[mat], HD, 4, tile, t & 63, Wf128 + (size_t)mat * 16384);
    } else if (b < 198) {
        const int tile = (b - 180) * 2 + (t >> 6);
        const int kc = tile & 3, nt = tile >> 2;
        const int L = t & 63;
        const int n = nt * 16 + (L & 15);
        const int kb = kc * 32 + (L >> 4) * 8;
        short v[8] __attribute__((aligned(16)));
        #pragma unroll
        for (int j = 0; j < 8; ++j)
            v[j] = (n < F_IN) ? (short)f2bf(W3[(size_t)(kb + j) * F_IN + n]) : (short)0;
        *(uint4*)(W3f + ((size_t)tile * 64 + L) * 8) = *(const uint4*)v;
    } else {
        __shared__ float sl[F_IN];
        const int l = b - 198;
        for (int f = t; f < F_IN; f += 128) sl[f] = lemb[l * F_IN + f];
        __syncthreads();
        float acc = b1[t] + b2[t];
        for (int f = 0; f < F_IN; ++f) acc += sl[f] * W2[f * HD + t];
        E[l * HD + t] = acc;
    }
}

// ---------------- kABC: kAB + layer-0 projections fused [R13-proven] ----------------
__global__ __launch_bounds__(256) void kABC(const float* __restrict__ feat,
        const short* __restrict__ Wf142, const short* __restrict__ W3f,
        const int* __restrict__ labels, const float* __restrict__ E,
        const float* __restrict__ bng, const float* __restrict__ bnb,
        const float* __restrict__ a3, const float* __restrict__ b3,
        const float* __restrict__ bq, const float* __restrict__ bk,
        const float* __restrict__ bv, const float* __restrict__ bsb,
        unsigned short* __restrict__ qh, unsigned short* __restrict__ kh,
        unsigned short* __restrict__ vh, float* __restrict__ sOut) {
    __shared__ float4 sAv[32 * 164 / 4];
    __shared__ uint4  sTv[32 * 136 / 8];
    __shared__ uint4  sHv[32 * 168 / 8];
    __shared__ int sLab[32];
    float* sA = (float*)sAv;
    unsigned short* sT = (unsigned short*)sTv;
    unsigned short* sH = (unsigned short*)sHv;
    const int tid = threadIdx.x;
    const int row0 = blockIdx.x * 32;
    for (int idx = tid; idx < 32 * F_IN; idx += 256) {
        int r = idx / F_IN, c = idx - r * F_IN;
        sA[r * 164 + c] = feat[(size_t)(row0 + r) * F_IN + c];
    }
    {   const int ZC = 160 - F_IN;
        for (int idx = tid; idx < 32 * ZC; idx += 256) {
            int r = idx / ZC, c = idx - r * ZC;
            sA[r * 164 + F_IN + c] = 0.f;
        }
    }
    if (tid < 32) sLab[tid] = labels[row0 + tid];
    __syncthreads();

    const int lane = tid & 63, w = tid >> 6;
    const int m = lane & 15, q = lane >> 4;
    const int nt0 = w * 2, nt1 = nt0 + 1;
    const int c0 = w * 32 + m, c1 = c0 + 16;

    {
        v4f acc00 = {0.f,0.f,0.f,0.f}, acc01 = acc00, acc10 = acc00, acc11 = acc00;
        #pragma unroll
        for (int kc = 0; kc < 5; ++kc) {
            const float* r0 = sA + m * 164 + kc * 32 + q * 8;
            const float* r1 = sA + (16 + m) * 164 + kc * 32 + q * 8;
            v8s a0 = pack8(*(const float4*)r0, *(const float4*)(r0 + 4));
            v8s a1 = pack8(*(const float4*)r1, *(const float4*)(r1 + 4));
            v8s b0 = *(const v8s*)(Wf142 + ((size_t)((nt0 * 5 + kc) * 64 + lane)) * 8);
            v8s b1 = *(const v8s*)(Wf142 + ((size_t)((nt1 * 5 + kc) * 64 + lane)) * 8);
            acc00 = __builtin_amdgcn_mfma_f32_16x16x32_bf16(a0, b0, acc00, 0, 0, 0);
            acc01 = __builtin_amdgcn_mfma_f32_16x16x32_bf16(a0, b1, acc01, 0, 0, 0);
            acc10 = __builtin_amdgcn_mfma_f32_16x16x32_bf16(a1, b0, acc10, 0, 0, 0);
            acc11 = __builtin_amdgcn_mfma_f32_16x16x32_bf16(a1, b1, acc11, 0, 0, 0);
        }
        const float g0 = bng[c0] * BN_SCALE, g1 = bng[c1] * BN_SCALE;
        const float bb0 = bnb[c0], bb1 = bnb[c1];
        const float al = a3[0];
        #pragma unroll
        for (int rt = 0; rt < 2; ++rt) {
            v4f A0 = rt ? acc10 : acc00;
            v4f A1 = rt ? acc11 : acc01;
            #pragma unroll
            for (int i = 0; i < 4; ++i) {
                const int r = rt * 16 + q * 4 + i;
                const int lab = sLab[r];
                float y0 = (A0[i] + E[lab * HD + c0]) * g0 + bb0;
                float y1 = (A1[i] + E[lab * HD + c1]) * g1 + bb1;
                y0 = (y0 >= 0.f) ? y0 : al * y0;
                y1 = (y1 >= 0.f) ? y1 : al * y1;
                sT[r * 136 + c0] = f2bf(y0);
                sT[r * 136 + c1] = f2bf(y1);
            }
        }
    }
    __syncthreads();

    {
        v4f d00 = {0.f,0.f,0.f,0.f}, d01 = d00, d10 = d00, d11 = d00, e0 = d00, e1 = d00;
        #pragma unroll
        for (int kc = 0; kc < 4; ++kc) {
            v8s a0 = *(const v8s*)(sT + m * 136 + kc * 32 + q * 8);
            v8s a1 = *(const v8s*)(sT + (16 + m) * 136 + kc * 32 + q * 8);
            v8s b0 = *(const v8s*)(W3f + ((size_t)((nt0 * 4 + kc) * 64 + lane)) * 8);
            v8s b1 = *(const v8s*)(W3f + ((size_t)((nt1 * 4 + kc) * 64 + lane)) * 8);
            d00 = __builtin_amdgcn_mfma_f32_16x16x32_bf16(a0, b0, d00, 0, 0, 0);
            d01 = __builtin_amdgcn_mfma_f32_16x16x32_bf16(a0, b1, d01, 0, 0, 0);
            d10 = __builtin_amdgcn_mfma_f32_16x16x32_bf16(a1, b0, d10, 0, 0, 0);
            d11 = __builtin_amdgcn_mfma_f32_16x16x32_bf16(a1, b1, d11, 0, 0, 0);
            if (w == 3) {
                v8s b2 = *(const v8s*)(W3f + ((size_t)((8 * 4 + kc) * 64 + lane)) * 8);
                e0 = __builtin_amdgcn_mfma_f32_16x16x32_bf16(a0, b2, e0, 0, 0, 0);
                e1 = __builtin_amdgcn_mfma_f32_16x16x32_bf16(a1, b2, e1, 0, 0, 0);
            }
        }
        const float b30 = b3[c0], b31 = b3[c1];
        #pragma unroll
        for (int rt = 0; rt < 2; ++rt) {
            v4f D0 = rt ? d10 : d00;
            v4f D1 = rt ? d11 : d01;
            #pragma unroll
            for (int i = 0; i < 4; ++i) {
                const int r = rt * 16 + q * 4 + i;
                sH[r * 168 + c0] = f2bf(sA[r * 164 + c0] + D0[i] + b30);
                sH[r * 168 + c1] = f2bf(sA[r * 164 + c1] + D1[i] + b31);
            }
        }
        if (w == 3) {
            const int c2 = 128 + m;
            const bool ok = (c2 < F_IN);
            const float b32 = ok ? b3[c2] : 0.f;
            #pragma unroll
            for (int i = 0; i < 4; ++i) {
                const int ra = q * 4 + i;
                const int rb = ra + 16;
                sH[ra * 168 + c2] = ok ? f2bf(sA[ra * 164 + c2] + e0[i] + b32) : (unsigned short)0;
                sH[rb * 168 + c2] = ok ? f2bf(sA[rb * 164 + c2] + e1[i] + b32) : (unsigned short)0;
            }
        }
        if (tid < 256) {
            const int r = tid >> 3, cp = tid & 7;
            ((unsigned*)sH)[r * 84 + 72 + cp] = 0u;
        }
    }
    __syncthreads();

    v8s afr0[5], afr1[5];
    #pragma unroll
    for (int kc = 0; kc < 5; ++kc) {
        afr0[kc] = *(const v8s*)(sH + m * 168 + kc * 32 + q * 8);
        afr1[kc] = *(const v8s*)(sH + (16 + m) * 168 + kc * 32 + q * 8);
    }
    #pragma unroll
    for (int mat = 0; mat < 4; ++mat) {
        const short* Wf = Wf142 + (size_t)(mat + 1) * 20480;
        const float* bias = (mat == 0) ? bq : (mat == 1) ? bk : (mat == 2) ? bv : bsb;
        v4f acc00 = {0.f,0.f,0.f,0.f}, acc01 = acc00, acc10 = acc00, acc11 = acc00;
        #pragma unroll
        for (int kc = 0; kc < 5; ++kc) {
            v8s b0 = *(const v8s*)(Wf + ((size_t)((nt0 * 5 + kc) * 64 + lane)) * 8);
            v8s b1 = *(const v8s*)(Wf + ((size_t)((nt1 * 5 + kc) * 64 + lane)) * 8);
            acc00 = __builtin_amdgcn_mfma_f32_16x16x32_bf16(afr0[kc], b0, acc00, 0, 0, 0);
            acc01 = __builtin_amdgcn_mfma_f32_16x16x32_bf16(afr0[kc], b1, acc01, 0, 0, 0);
            acc10 = __builtin_amdgcn_mfma_f32_16x16x32_bf16(afr1[kc], b0, acc10, 0, 0, 0);
            acc11 = __builtin_amdgcn_mfma_f32_16x16x32_bf16(afr1[kc], b1, acc11, 0, 0, 0);
        }
        const float b0v = bias[c0], b1v = bias[c1];
        if (mat < 3) {
            unsigned short* outh = (mat == 0) ? qh : (mat == 1) ? kh : vh;
            unsigned short* outw = outh + ((size_t)w * N_NODES + row0) * DHEAD;
            #pragma unroll
            for (int rt = 0; rt < 2; ++rt) {
                v4f A0 = rt ? acc10 : acc00;
                v4f A1 = rt ? acc11 : acc01;
                #pragma unroll
                for (int i = 0; i < 4; ++i) {
                    const int r = rt * 16 + q * 4 + i;
                    outw[(size_t)r * DHEAD + m]      = f2bf(A0[i] + b0v);
                    outw[(size_t)r * DHEAD + 16 + m] = f2bf(A1[i] + b1v);
                }
            }
        } else {
            #pragma unroll
            for (int rt = 0; rt < 2; ++rt) {
                v4f A0 = rt ? acc10 : acc00;
                v4f A1 = rt ? acc11 : acc01;
                #pragma unroll
                for (int i = 0; i < 4; ++i) {
                    const int r = rt * 16 + q * 4 + i;
                    sOut[(size_t)(row0 + r) * HD + c0] = A0[i] + b0v;
                    sOut[(size_t)(row0 + r) * HD + c1] = A1[i] + b1v;
                }
            }
        }
    }
}

// ---- fused kE phase [R13-proven] ----
__device__ __forceinline__ void kE_phase(const float* __restrict__ skip,
        const float* __restrict__ agg, const float* __restrict__ Wg,
        const float* __restrict__ bg, const float* __restrict__ lng,
        const float* __restrict__ lnb, const float* __restrict__ ac,
        float* sA, int row0, int t) {
    const int e = t & 31, g8 = t >> 5;
    const float al = ac[0];
    const float bg0 = bg[0];
    for (int ng = 0; ng < 4; ++ng) {
        const int j = ng * 8 + g8;
        const size_t n = (size_t)(row0 + j);
        float skv[4], agv[4];
        float part = 0.f;
        #pragma unroll
        for (int k2 = 0; k2 < 4; ++k2) {
            const int c = e + 32 * k2;
            skv[k2] = skip[n * HD + c];
            agv[k2] = agg[n * HD + c];
            part += skv[k2] * Wg[c] + agv[k2] * Wg[HD + c] + (skv[k2] - agv[k2]) * Wg[2 * HD + c];
        }
        #pragma unroll
        for (int off = 16; off > 0; off >>= 1)
            part += __shfl_xor(part, off, 32);
        const float g = 1.f / (1.f + expf(-(part + bg0)));
        float rv[4], rsum = 0.f;
        #pragma unroll
        for (int k2 = 0; k2 < 4; ++k2) {
            rv[k2] = g * skv[k2] + (1.f - g) * agv[k2];
            rsum += rv[k2];
        }
        #pragma unroll
        for (int off = 16; off > 0; off >>= 1)
            rsum += __shfl_xor(rsum, off, 32);
        const float mean = rsum * (1.f / HD);
        float dv[4], vsum = 0.f;
        #pragma unroll
        for (int k2 = 0; k2 < 4; ++k2) {
            dv[k2] = rv[k2] - mean;
            vsum += dv[k2] * dv[k2];
        }
        #pragma unroll
        for (int off = 16; off > 0; off >>= 1)
            vsum += __shfl_xor(vsum, off, 32);
        const float inv = rsqrtf(vsum * (1.f / HD) + 1e-5f);
        #pragma unroll
        for (int k2 = 0; k2 < 4; ++k2) {
            const int c = e + 32 * k2;
            float y = dv[k2] * inv * lng[c] + lnb[c];
            sA[j * 132 + c] = (y >= 0.f) ? y : al * y;
        }
    }
}

// ---------------- kEC4: layer-0 kE + layer-1 projections [R13-proven] ----------------
__global__ __launch_bounds__(256) void kEC4(const float* __restrict__ skip,
        const float* __restrict__ agg,
        const float* __restrict__ Wg, const float* __restrict__ bg,
        const float* __restrict__ lng, const float* __restrict__ lnb,
        const float* __restrict__ ac,
        const short* __restrict__ Wf128,
        const float* __restrict__ bq, const float* __restrict__ bk,
        const float* __restrict__ bv, const float* __restrict__ bsb,
        unsigned short* __restrict__ qh, unsigned short* __restrict__ kh,
        unsigned short* __restrict__ vh, float* __restrict__ sOut) {
    __shared__ float4 sAv[32 * 132 / 4];
    float* sA = (float*)sAv;
    const int tid = threadIdx.x;
    const int row0 = blockIdx.x * 32;
    kE_phase(skip, agg, Wg, bg, lng, lnb, ac, sA, row0, tid);
    __syncthreads();

    const int lane = tid & 63, w = tid >> 6;
    const int m = lane & 15, q = lane >> 4;
    const int nt0 = w * 2, nt1 = nt0 + 1;
    v8s afr0[4], afr1[4];
    #pragma unroll
    for (int kc = 0; kc < 4; ++kc) {
        const float* r0 = sA + m * 132 + kc * 32 + q * 8;
        const float* r1 = sA + (16 + m) * 132 + kc * 32 + q * 8;
        afr0[kc] = pack8(*(const float4*)r0, *(const float4*)(r0 + 4));
        afr1[kc] = pack8(*(const float4*)r1, *(const float4*)(r1 + 4));
    }
    const int c0 = w * 32 + m, c1 = c0 + 16;
    #pragma unroll
    for (int mat = 0; mat < 4; ++mat) {
        const short* Wf = Wf128 + (size_t)mat * 16384;
        const float* bias = (mat == 0) ? bq : (mat == 1) ? bk : (mat == 2) ? bv : bsb;
        v4f acc00 = {0.f,0.f,0.f,0.f}, acc01 = acc00, acc10 = acc00, acc11 = acc00;
        #pragma unroll
        for (int kc = 0; kc < 4; ++kc) {
            v8s b0 = *(const v8s*)(Wf + ((size_t)((nt0 * 4 + kc) * 64 + lane)) * 8);
            v8s b1 = *(const v8s*)(Wf + ((size_t)((nt1 * 4 + kc) * 64 + lane)) * 8);
            acc00 = __builtin_amdgcn_mfma_f32_16x16x32_bf16(afr0[kc], b0, acc00, 0, 0, 0);
            acc01 = __builtin_amdgcn_mfma_f32_16x16x32_bf16(afr0[kc], b1, acc01, 0, 0, 0);
            acc10 = __builtin_amdgcn_mfma_f32_16x16x32_bf16(afr1[kc], b0, acc10, 0, 0, 0);
            acc11 = __builtin_amdgcn_mfma_f32_16x16x32_bf16(afr1[kc], b1, acc11, 0, 0, 0);
        }
        const float b0v = bias[c0], b1v = bias[c1];
        if (mat < 3) {
            unsigned short* outh = (mat == 0) ? qh : (mat == 1) ? kh : vh;
            unsigned short* outw = outh + ((size_t)w * N_NODES + row0) * DHEAD;
            #pragma unroll
            for (int rt = 0; rt < 2; ++rt) {
                v4f A0 = rt ? acc10 : acc00;
                v4f A1 = rt ? acc11 : acc01;
                #pragma unroll
                for (int i = 0; i < 4; ++i) {
                    const int r = rt * 16 + q * 4 + i;
                    outw[(size_t)r * DHEAD + m]      = f2bf(A0[i] + b0v);
                    outw[(size_t)r * DHEAD + 16 + m] = f2bf(A1[i] + b1v);
                }
            }
        } else {
            #pragma unroll
            for (int rt = 0; rt < 2; ++rt) {
                v4f A0 = rt ? acc10 : acc00;
                v4f A1 = rt ? acc11 : acc01;
                #pragma unroll
                for (int i = 0; i < 4; ++i) {
                    const int r = rt * 16 + q * 4 + i;
                    sOut[(size_t)(row0 + r) * HD + c0] = A0[i] + b0v;
                    sOut[(size_t)(row0 + r) * HD + c1] = A1[i] + b1v;
                }
            }
        }
    }
}

// ---------------- kD_x: head-split attention, XCD-aware head partitioning ----------------
// 1D grid of 10000 blocks. Block b: xcd-slot = b&7 -> head = (b&7)>>1; node group
// g = (b>>3)*2 + (b&1). Under round-robin block->XCD dispatch, each head's q/v
// slices are pulled by only 2 XCDs (2.56 MB < 4 MiB L2) instead of all 8.
// Body is byte-identical to the proven kD_h.
__global__ __launch_bounds__(256) void kD_x(const unsigned short* __restrict__ qh,
        const unsigned short* __restrict__ kh, const unsigned short* __restrict__ vh,
        const int* __restrict__ esrc, float* __restrict__ agg) {
    __shared__ float sk[8][DHEAD];
    __shared__ int ssrc[8][DEG];
    __shared__ float sa[8][DEG];
    const int b = blockIdx.x;
    const int x = b & 7;
    const int h = x >> 1;
    const int n0 = ((b >> 3) * 2 + (x & 1)) * 8;
    const int t = threadIdx.x;
    const int j = t >> 5, e = t & 31;

    ssrc[j][e] = esrc[n0 * DEG + t];
    if (t < 128) {
        unsigned u = *((const unsigned*)(kh + ((size_t)h * N_NODES + n0) * DHEAD) + t);
        float* skf = &sk[0][0];
        skf[2 * t]     = bflo(u);
        skf[2 * t + 1] = bfhi(u);
    }
    __syncthreads();

    const int src = ssrc[j][e];
    const uint4* qp = (const uint4*)(qh + ((size_t)h * N_NODES + src) * DHEAD);
    const float* kj = sk[j];
    float sc = 0.f;
    #pragma unroll
    for (int i = 0; i < 4; ++i) {
        uint4 u = qp[i];
        sc = fmaf(bflo(u.x), kj[i * 8 + 0], sc);
        sc = fmaf(bfhi(u.x), kj[i * 8 + 1], sc);
        sc = fmaf(bflo(u.y), kj[i * 8 + 2], sc);
        sc = fmaf(bfhi(u.y), kj[i * 8 + 3], sc);
        sc = fmaf(bflo(u.z), kj[i * 8 + 4], sc);
        sc = fmaf(bfhi(u.z), kj[i * 8 + 5], sc);
        sc = fmaf(bflo(u.w), kj[i * 8 + 6], sc);
        sc = fmaf(bfhi(u.w), kj[i * 8 + 7], sc);
    }
    sc *= INV_SQRT_D;
    float m = sc;
    #pragma unroll
    for (int off = 16; off > 0; off >>= 1)
        m = fmaxf(m, __shfl_xor(m, off, 32));
    float p = expf(sc - m);
    float ssum = p;
    #pragma unroll
    for (int off = 16; off > 0; off >>= 1)
        ssum += __shfl_xor(ssum, off, 32);
    sa[j][e] = p / ssum;
    __syncthreads();

    const int d = t & 31;
    const unsigned short* vbase = vh + (size_t)h * N_NODES * DHEAD + d;
    float acc = 0.f;
    #pragma unroll
    for (int e2 = 0; e2 < DEG; ++e2) {
        const int s2 = ssrc[j][e2];
        acc = fmaf(bf2f(vbase[(size_t)s2 * DHEAD]), sa[j][e2], acc);
    }
    agg[(size_t)(n0 + j) * HD + h * DHEAD + d] = acc;
}

// ---------------- kEF: layer-1 kE + kF fused [R13-proven] ----------------
__global__ __launch_bounds__(256) void kEF(const float* __restrict__ skip,
        const float* __restrict__ agg,
        const float* __restrict__ Wg, const float* __restrict__ bg,
        const float* __restrict__ lng, const float* __restrict__ lnb,
        const float* __restrict__ ac,
        const short* __restrict__ W4f, const float* __restrict__ b4,
        const float* __restrict__ bng, const float* __restrict__ bnb,
        const float* __restrict__ a5, const float* __restrict__ W5,
        const float* __restrict__ b5, float* __restrict__ out) {
    __shared__ float4 sAv[32 * 132 / 4];
    float* sA = (float*)sAv;
    const int tid = threadIdx.x;
    const int row0 = blockIdx.x * 32;
    kE_phase(skip, agg, Wg, bg, lng, lnb, ac, sA, row0, tid);
    __syncthreads();

    const int lane = tid & 63, w = tid >> 6;
    const int m = lane & 15, q = lane >> 4;
    const int nt0 = w * 2, nt1 = nt0 + 1;
    v4f acc00 = {0.f,0.f,0.f,0.f}, acc01 = acc00, acc10 = acc00, acc11 = acc00;
    #pragma unroll
    for (int kc = 0; kc < 4; ++kc) {
        const float* r0 = sA + m * 132 + kc * 32 + q * 8;
        const float* r1 = sA + (16 + m) * 132 + kc * 32 + q * 8;
        v8s a0 = pack8(*(const float4*)r0, *(const float4*)(r0 + 4));
        v8s a1 = pack8(*(const float4*)r1, *(const float4*)(r1 + 4));
        v8s b0 = *(const v8s*)(W4f + ((size_t)((nt0 * 4 + kc) * 64 + lane)) * 8);
        v8s b1 = *(const v8s*)(W4f + ((size_t)((nt1 * 4 + kc) * 64 + lane)) * 8);
        acc00 = __builtin_amdgcn_mfma_f32_16x16x32_bf16(a0, b0, acc00, 0, 0, 0);
        acc01 = __builtin_amdgcn_mfma_f32_16x16x32_bf16(a0, b1, acc01, 0, 0, 0);
        acc10 = __builtin_amdgcn_mfma_f32_16x16x32_bf16(a1, b0, acc10, 0, 0, 0);
        acc11 = __builtin_amdgcn_mfma_f32_16x16x32_bf16(a1, b1, acc11, 0, 0, 0);
    }
    __syncthreads();
    const int c0 = w * 32 + m, c1 = c0 + 16;
    const float g0 = bng[c0] * BN_SCALE, g1 = bng[c1] * BN_SCALE;
    const float bb0 = bnb[c0], bb1 = bnb[c1];
    const float b40 = b4[c0], b41 = b4[c1];
    const float al = a5[0];
    #pragma unroll
    for (int rt = 0; rt < 2; ++rt) {
        v4f A0 = rt ? acc10 : acc00;
        v4f A1 = rt ? acc11 : acc01;
        #pragma unroll
        for (int i = 0; i < 4; ++i) {
            const int r = rt * 16 + q * 4 + i;
            float y0 = (A0[i] + b40) * g0 + bb0;
            float y1 = (A1[i] + b41) * g1 + bb1;
            y0 = (y0 >= 0.f) ? y0 : al * y0;
            y1 = (y1 >= 0.f) ? y1 : al * y1;
            sA[r * 132 + c0] = y0;
            sA[r * 132 + c1] = y1;
        }
    }
    __syncthreads();
    if (tid < 64) {
        const int r = tid >> 1, cls = tid & 1;
        const float* yr = sA + r * 132;
        float s = b5[cls];
        #pragma unroll 8
        for (int c = 0; c < HD; ++c)
            s = fmaf(yr[c], W5[c * 2 + cls], s);
        out[(size_t)(row0 + r) * N_CLS + cls] = s;
    }
}

extern "C" void kernel_launch(void* const* d_in, const int* in_sizes, int n_in,
                              void* d_out, int out_size, void* d_ws, size_t ws_size,
                              hipStream_t stream) {
    const float* feat  = (const float*)d_in[0];
    const float* lemb  = (const float*)d_in[1];
    const float* W1    = (const float*)d_in[2];
    const float* b1    = (const float*)d_in[3];
    const float* W2    = (const float*)d_in[4];
    const float* b2    = (const float*)d_in[5];
    const float* bn0g  = (const float*)d_in[6];
    const float* bn0b  = (const float*)d_in[7];
    const float* a3    = (const float*)d_in[8];
    const float* W3    = (const float*)d_in[9];
    const float* b3    = (const float*)d_in[10];
    const float* aconv = (const float*)d_in[35];
    const float* W4    = (const float*)d_in[36];
    const float* b4    = (const float*)d_in[37];
    const float* bn1g  = (const float*)d_in[38];
    const float* bn1b  = (const float*)d_in[39];
    const float* a5    = (const float*)d_in[40];
    const float* W5    = (const float*)d_in[41];
    const float* b5    = (const float*)d_in[42];
    const int*   labels = (const int*)d_in[43];
    const int*   esrc   = (const int*)d_in[44];

    char* ws = (char*)d_ws;
    float* bs  = (float*)ws;                       ws += sizeof(float) * N_NODES * HD;
    float* bag = (float*)ws;                       ws += sizeof(float) * N_NODES * HD;
    unsigned short* bqh = (unsigned short*)ws;     ws += sizeof(short) * N_NODES * HD;
    unsigned short* bkh = (unsigned short*)ws;     ws += sizeof(short) * N_NODES * HD;
    unsigned short* bvh = (unsigned short*)ws;     ws += sizeof(short) * N_NODES * HD;
    short* Wf142 = (short*)ws;                     ws += sizeof(short) * 5 * 20480;
    short* Wf128 = (short*)ws;                     ws += sizeof(short) * 5 * 16384;
    short* W3f = (short*)ws;                       ws += sizeof(short) * 36 * 512;
    float* bE  = (float*)ws;                       ws += sizeof(float) * 3 * HD;
    float* out = (float*)d_out;

    dim3 gT(N_NODES / 32);
    dim3 gDx(N_NODES / 8 * NHEAD);   // 10000, 1D with XCD-aware decode

    kPrep<<<dim3(201), 128, 0, stream>>>(
        W1, (const float*)d_in[11], (const float*)d_in[13],
        (const float*)d_in[15], (const float*)d_in[17],
        (const float*)d_in[23], (const float*)d_in[25],
        (const float*)d_in[27], (const float*)d_in[29], W4,
        W3, lemb, W2, b1, b2,
        Wf142, Wf128, W3f, bE);

    kABC<<<gT, 256, 0, stream>>>(feat, Wf142, W3f, labels, bE, bn0g, bn0b, a3, b3,
        (const float*)d_in[12], (const float*)d_in[14],
        (const float*)d_in[16], (const float*)d_in[18],
        bqh, bkh, bvh, bs);
    kD_x<<<gDx, 256, 0, stream>>>(bqh, bkh, bvh, esrc, bag);

    kEC4<<<gT, 256, 0, stream>>>(bs, bag,
        (const float*)d_in[19], (const float*)d_in[20],
        (const float*)d_in[21], (const float*)d_in[22], aconv,
        Wf128,
        (const float*)d_in[24], (const float*)d_in[26],
        (const float*)d_in[28], (const float*)d_in[30],
        bqh, bkh, bvh, bs);
    kD_x<<<gDx, 256, 0, stream>>>(bqh, bkh, bvh, esrc, bag);

    kEF<<<gT, 256, 0, stream>>>(bs, bag,
        (const float*)d_in[31], (const float*)d_in[32],
        (const float*)d_in[33], (const float*)d_in[34], aconv,
        Wf128 + 4 * 16384, b4, bn1g, bn1b, a5, W5, b5, out);
}